// Round 13
// baseline (250.760 us; speedup 1.0000x reference)
//
#include <hip/hip_runtime.h>
#include <hip/hip_bf16.h>

#define NEG_SLOPE 0.2f
#define PAD 64          // padded CSR row; slot 0 = self-loop, slots 1..63 = edges
#define NBNODE 128      // dst nodes per bucket
#define CHUNK 4096      // edges per sort block

__device__ __forceinline__ float lrelu(float x){ return x >= 0.f ? x : NEG_SLOPE * x; }

__device__ __forceinline__ unsigned pack_bf16(float a, float b){
  unsigned ua = __float_as_uint(a), ub = __float_as_uint(b);
  ua = (ua + 0x7fffu + ((ua >> 16) & 1u)) >> 16;
  ub = (ub + 0x7fffu + ((ub >> 16) & 1u)) >> 16;
  return ua | (ub << 16);
}
__device__ __forceinline__ float bflo(unsigned u){ return __uint_as_float(u << 16); }
__device__ __forceinline__ float bfhi(unsigned u){ return __uint_as_float(u & 0xffff0000u); }

// ---------------- fused: chunk bucket-sort (no global atomics) + layer1 linear ----------------
// blockIdx % M == 0 -> sort chunk (4096 edges); else -> lin1 (32 nodes, W1 in VGPRs).
__global__ __launch_bounds__(256) void k_bl1(const int* __restrict__ ei, int E, int N,
        int nbk, int nblk, int M,
        int* __restrict__ offs, unsigned* __restrict__ ebuf,
        const int* __restrict__ x_ids, const float* __restrict__ item_emb,
        const float* __restrict__ W1, const float* __restrict__ att_s, const float* __restrict__ att_d,
        unsigned* __restrict__ h1bf, float* __restrict__ a_src, float* __restrict__ a_dst){
  int b = blockIdx.x;
  int t = threadIdx.x;
  int lane = t & 63, wid = t >> 6;
  if (b % M == 0){
    int c = b / M;
    if (c >= nblk) return;
    __shared__ int lh[1024];     // histogram, then cursors
    __shared__ int st[1025];     // exclusive starts
    __shared__ int ws5[5];
    for (int i = t; i < nbk; i += 256) lh[i] = 0;
    __syncthreads();
    int ce = c * CHUNK;
    int cnt = E - ce; if (cnt > CHUNK) cnt = CHUNK;
    #pragma unroll
    for (int i = 0; i < 16; ++i){
      int e = t + i * 256;
      if (e < cnt){
        int d = ei[E + ce + e];
        atomicAdd(&lh[d >> 7], 1);
      }
    }
    __syncthreads();
    // exclusive scan lh[0..nbk-1] -> st[0..nbk]
    int idx0 = t * 4;
    int v0 = 0, v1 = 0, v2 = 0, v3 = 0;
    if (idx0     < nbk) v0 = lh[idx0];
    if (idx0 + 1 < nbk) v1 = lh[idx0 + 1];
    if (idx0 + 2 < nbk) v2 = lh[idx0 + 2];
    if (idx0 + 3 < nbk) v3 = lh[idx0 + 3];
    int ts = v0 + v1 + v2 + v3;
    int x = ts;
    #pragma unroll
    for (int off = 1; off < 64; off <<= 1){
      int y = __shfl_up(x, off);
      if (lane >= off) x += y;
    }
    if (lane == 63) ws5[wid] = x;
    __syncthreads();
    if (t == 0){
      int a = 0;
      #pragma unroll
      for (int k = 0; k < 4; ++k){ int tmp = ws5[k]; ws5[k] = a; a += tmp; }
      ws5[4] = a;
      st[nbk] = a;
    }
    __syncthreads();
    int ex = x - ts + ws5[wid];
    if (idx0     < nbk) st[idx0]     = ex;
    if (idx0 + 1 < nbk) st[idx0 + 1] = ex + v0;
    if (idx0 + 2 < nbk) st[idx0 + 2] = ex + v0 + v1;
    if (idx0 + 3 < nbk) st[idx0 + 3] = ex + v0 + v1 + v2;
    __syncthreads();
    for (int i = t; i < nbk; i += 256) lh[i] = st[i];          // cursors
    for (int i = t; i <= nbk; i += 256) offs[(size_t)c * (nbk + 1) + i] = st[i];
    __syncthreads();
    #pragma unroll
    for (int i = 0; i < 16; ++i){
      int e = t + i * 256;
      if (e < cnt){
        int s = ei[ce + e];
        int d = ei[E + ce + e];
        int r = atomicAdd(&lh[d >> 7], 1);
        ebuf[(size_t)ce + r] = (unsigned)s | ((unsigned)(d & 127) << 17);
      }
    }
    return;
  }
  // ---- lin1: W1 column-pair in registers, readlane broadcast, LDS-free ----
  int lid = (b / M) * (M - 1) + (b % M) - 1;
  int base = lid * 32 + wid * 8;
  if (base >= N) return;
  float2 w1c[32];
  const float2* W12 = (const float2*)W1;
  #pragma unroll
  for (int k = 0; k < 32; ++k) w1c[k] = W12[(k << 6) + lane];
  int c0 = 2 * lane;
  float as0 = att_s[c0], as1 = att_s[c0 + 1];
  float ad0 = att_d[c0], ad1 = att_d[c0 + 1];
  for (int it = 0; it < 8; ++it){
    int n = base + it;
    if (n >= N) break;
    float xv = 0.f;
    if (lane < 32){
      int id = x_ids[n];
      xv = (id == 0) ? 0.f : item_emb[(size_t)id * 32 + lane];
    }
    float acc0 = 0.f, acc1 = 0.f;
    #pragma unroll
    for (int k = 0; k < 32; ++k){
      float xk = __uint_as_float(__builtin_amdgcn_readlane(__float_as_uint(xv), k));
      acc0 += xk * w1c[k].x;
      acc1 += xk * w1c[k].y;
    }
    h1bf[(size_t)n * 64 + lane] = pack_bf16(acc0, acc1);
    float ps = acc0 * as0 + acc1 * as1;
    float pd = acc0 * ad0 + acc1 * ad1;
    #pragma unroll
    for (int off = 16; off; off >>= 1){
      ps += __shfl_xor(ps, off);
      pd += __shfl_xor(pd, off);
    }
    if ((lane & 31) == 0){
      int head = lane >> 5;
      a_src[n * 2 + head] = ps;
      a_dst[n * 2 + head] = pd;
    }
  }
}

// ---------------- per-bucket CSR build in LDS, coalesced global write ----------------
__global__ __launch_bounds__(256) void k_build(const int* __restrict__ offs,
        const unsigned* __restrict__ ebuf, int N, int nbk, int nblk,
        int* __restrict__ deg, int* __restrict__ csr){
  __shared__ int lcsr[NBNODE * PAD];   // 32 KB
  __shared__ int ldeg[NBNODE];
  int b = blockIdx.x, t = threadIdx.x;
  int base = b * NBNODE;
  int nn = N - base; if (nn > NBNODE) nn = NBNODE;
  for (int i = t; i < NBNODE; i += 256) ldeg[i] = 0;
  __syncthreads();
  for (int c = t; c < nblk; c += 256){
    size_t ob = (size_t)c * (nbk + 1) + b;
    int o0 = offs[ob];
    int o1 = offs[ob + 1];
    size_t ce = (size_t)c * CHUNK;
    for (int i = o0; i < o1; ++i){
      unsigned u = ebuf[ce + i];
      int ld = (int)(u >> 17);
      int s  = (int)(u & 0x1FFFFu);
      int slot = 1 + atomicAdd(&ldeg[ld], 1);
      if (slot < PAD) lcsr[(ld << 6) + slot] = s;
    }
  }
  __syncthreads();
  for (int i = t; i < nn; i += 256){
    int dv = ldeg[i];
    deg[base + i] = (dv > PAD - 1) ? (PAD - 1) : dv;
  }
  const uint4* l4 = (const uint4*)lcsr;
  uint4* g4 = (uint4*)(csr + ((size_t)base << 6));
  int n4 = nn * 16;
  for (int i = t; i < n4; i += 256) g4[i] = l4[i];
}

#define FMA8(P, V) \
  acc[0] += (P) * bflo((V).x); acc[1] += (P) * bfhi((V).x); \
  acc[2] += (P) * bflo((V).y); acc[3] += (P) * bfhi((V).y); \
  acc[4] += (P) * bflo((V).z); acc[5] += (P) * bfhi((V).z); \
  acc[6] += (P) * bflo((V).w); acc[7] += (P) * bfhi((V).w);

// ---------------- layer 1 fused attention + aggregation (bf16 rows in & out) ----------------
// wave per dst node; 4-deep unroll; packed-p shfl + 32-bit OR addressing.
__global__ __launch_bounds__(256) void k_gat1(const int* __restrict__ deg, const int* __restrict__ csr,
        const float* __restrict__ a_src, const float* __restrict__ a_dst,
        const unsigned* __restrict__ hbf, const float* __restrict__ bias,
        unsigned* __restrict__ h1p, int N){
  int w = blockIdx.x * 4 + (threadIdx.x >> 6);
  int lane = threadIdx.x & 63;
  if (w >= N) return;
  int cnt = deg[w]; if (cnt > PAD - 1) cnt = PAD - 1;
  int dg = cnt + 1;
  int src_l = (lane == 0) ? w : csr[((size_t)w << 6) + lane];
  float2 ad = ((const float2*)a_dst)[w];
  float e0 = -__builtin_inff(), e1 = -__builtin_inff();
  if (lane < dg){
    float2 as = ((const float2*)a_src)[src_l];
    e0 = lrelu(as.x + ad.x);
    e1 = lrelu(as.y + ad.y);
  }
  float m0 = e0, m1 = e1;
  #pragma unroll
  for (int off = 32; off; off >>= 1){
    m0 = fmaxf(m0, __shfl_xor(m0, off));
    m1 = fmaxf(m1, __shfl_xor(m1, off));
  }
  float p0 = __expf(e0 - m0);
  float p1 = __expf(e1 - m1);
  float s0 = p0, s1 = p1;
  #pragma unroll
  for (int off = 32; off; off >>= 1){
    s0 += __shfl_xor(s0, off);
    s1 += __shfl_xor(s1, off);
  }
  float inv0 = 1.f / (s0 + 1e-16f);
  float inv1 = 1.f / (s1 + 1e-16f);
  unsigned ppk = pack_bf16(p0, p1);       // bf16 pair for one-shfl broadcast

  int g  = lane >> 4;            // edge group 0..3
  int sl = lane & 15;            // 16B slot in 256B row
  unsigned slb = (unsigned)sl * 16u;
  const char* hb = (const char*)hbf;
  float acc[8];
  #pragma unroll
  for (int i = 0; i < 8; ++i) acc[i] = 0.f;
  for (int i = 0; i < dg; i += 16){
    int jA = i + g, jB = i + 4 + g, jC = i + 8 + g, jD = i + 12 + g;
    int sA = __shfl(src_l, jA); unsigned kA = (unsigned)__shfl((int)ppk, jA);
    int sB = __shfl(src_l, jB); unsigned kB = (unsigned)__shfl((int)ppk, jB);
    int sC = __shfl(src_l, jC); unsigned kC = (unsigned)__shfl((int)ppk, jC);
    int sD = __shfl(src_l, jD); unsigned kD = (unsigned)__shfl((int)ppk, jD);
    float pA = (sl < 8) ? bflo(kA) : bfhi(kA); if (jA >= dg){ pA = 0.f; sA = 0; }
    float pB = (sl < 8) ? bflo(kB) : bfhi(kB); if (jB >= dg){ pB = 0.f; sB = 0; }
    float pC = (sl < 8) ? bflo(kC) : bfhi(kC); if (jC >= dg){ pC = 0.f; sC = 0; }
    float pD = (sl < 8) ? bflo(kD) : bfhi(kD); if (jD >= dg){ pD = 0.f; sD = 0; }
    uint4 vA = *(const uint4*)(hb + ((((unsigned)sA) << 8) | slb));
    uint4 vB = *(const uint4*)(hb + ((((unsigned)sB) << 8) | slb));
    uint4 vC = *(const uint4*)(hb + ((((unsigned)sC) << 8) | slb));
    uint4 vD = *(const uint4*)(hb + ((((unsigned)sD) << 8) | slb));
    FMA8(pA, vA)
    FMA8(pB, vB)
    FMA8(pC, vC)
    FMA8(pD, vD)
  }
  #pragma unroll
  for (int off = 16; off <= 32; off <<= 1){
    #pragma unroll
    for (int i = 0; i < 8; ++i) acc[i] += __shfl_xor(acc[i], off);
  }
  if (lane < 16){
    float inv = (sl < 8) ? inv0 : inv1;
    float4 b0 = ((const float4*)bias)[2 * sl];
    float4 b1 = ((const float4*)bias)[2 * sl + 1];
    float r0 = fmaxf(acc[0] * inv + b0.x, 0.f);
    float r1 = fmaxf(acc[1] * inv + b0.y, 0.f);
    float r2 = fmaxf(acc[2] * inv + b0.z, 0.f);
    float r3 = fmaxf(acc[3] * inv + b0.w, 0.f);
    float r4 = fmaxf(acc[4] * inv + b1.x, 0.f);
    float r5 = fmaxf(acc[5] * inv + b1.y, 0.f);
    float r6 = fmaxf(acc[6] * inv + b1.z, 0.f);
    float r7 = fmaxf(acc[7] * inv + b1.w, 0.f);
    uint4 pk;
    pk.x = pack_bf16(r0, r1);
    pk.y = pack_bf16(r2, r3);
    pk.z = pack_bf16(r4, r5);
    pk.w = pack_bf16(r6, r7);
    ((uint4*)h1p)[(size_t)w * 16 + sl] = pk;
  }
}

// ---------------- layer 2 linear + attention dots ----------------
// 32 nodes/block (2 passes of 16). W2 as packed-bf16 in LDS (16KB);
// h rows staged as raw bf16-pair uints, stride 65 (bank-conflict-free).
__global__ __launch_bounds__(256) void k_lin2(const unsigned* __restrict__ h1p, const float* __restrict__ W2,
        const float* __restrict__ att_s, const float* __restrict__ att_d,
        unsigned* __restrict__ h2bf, float* __restrict__ a_src, float* __restrict__ a_dst, int N){
  int t = threadIdx.x;
  __shared__ unsigned W2s[128 * 32];   // 16 KB: row k, uint c = cols 2c,2c+1 (bf16)
  __shared__ unsigned hsu[16 * 65];    // 16 node rows, 64 uints each, +1 pad
  #pragma unroll
  for (int i = 0; i < 16; ++i){
    int u = t + i * 256;               // u = k*32 + c
    float2 w = ((const float2*)W2)[u];
    W2s[u] = pack_bf16(w.x, w.y);
  }
  int node16 = t >> 4;                 // 0..15
  int c4 = t & 15;                     // col group: cols 4c4..4c4+3
  float4 asv = ((const float4*)att_s)[c4];
  float4 adv = ((const float4*)att_d)[c4];
  int base = blockIdx.x * 32;
  for (int p = 0; p < 2; ++p){
    int nb16 = base + p * 16;
    __syncthreads();
    #pragma unroll
    for (int i = 0; i < 4; ++i){
      int idx = t + i * 256;           // 1024 uints
      int nd = idx >> 6, ku = idx & 63;
      int n = nb16 + nd;
      hsu[nd * 65 + ku] = (n < N) ? h1p[(size_t)n * 64 + ku] : 0u;
    }
    __syncthreads();
    int n = nb16 + node16;
    if (n >= N) continue;
    float a0 = 0.f, a1 = 0.f, a2 = 0.f, a3 = 0.f;
    const unsigned* hrow = hsu + node16 * 65;
    #pragma unroll 8
    for (int ku = 0; ku < 64; ++ku){
      unsigned hv = hrow[ku];
      float h0 = bflo(hv), h1 = bfhi(hv);
      int r0 = (ku << 6) + 2 * c4;     // uint idx: row k0=2ku
      unsigned wa = W2s[r0],      wb = W2s[r0 + 1];
      unsigned wc = W2s[r0 + 32], wd = W2s[r0 + 33];   // row k1=2ku+1
      a0 += h0 * bflo(wa) + h1 * bflo(wc);
      a1 += h0 * bfhi(wa) + h1 * bfhi(wc);
      a2 += h0 * bflo(wb) + h1 * bflo(wd);
      a3 += h0 * bfhi(wb) + h1 * bfhi(wd);
    }
    uint2 pk;
    pk.x = pack_bf16(a0, a1);
    pk.y = pack_bf16(a2, a3);
    ((uint2*)h2bf)[(size_t)n * 16 + c4] = pk;
    float ps = a0 * asv.x + a1 * asv.y + a2 * asv.z + a3 * asv.w;
    float pd = a0 * adv.x + a1 * adv.y + a2 * adv.z + a3 * adv.w;
    #pragma unroll
    for (int off = 8; off; off >>= 1){
      ps += __shfl_xor(ps, off);
      pd += __shfl_xor(pd, off);
    }
    if (c4 == 0){ a_src[n] = ps; a_dst[n] = pd; }
  }
}

// ---------------- layer 2 fused attention + aggregation (bf16 rows) ----------------
// wave per dst node; 2-deep unroll; 32-bit OR addressing.
__global__ __launch_bounds__(256) void k_gat2(const int* __restrict__ deg, const int* __restrict__ csr,
        const float* __restrict__ a_src, const float* __restrict__ a_dst,
        const unsigned* __restrict__ hbf, const float* __restrict__ bias,
        float* __restrict__ dout, int N){
  int w = blockIdx.x * 4 + (threadIdx.x >> 6);
  int lane = threadIdx.x & 63;
  if (w >= N) return;
  int cnt = deg[w]; if (cnt > PAD - 1) cnt = PAD - 1;
  int dg = cnt + 1;
  int src_l = (lane == 0) ? w : csr[((size_t)w << 6) + lane];
  float ad = a_dst[w];
  float e = -__builtin_inff();
  if (lane < dg) e = lrelu(a_src[src_l] + ad);
  float m = e;
  #pragma unroll
  for (int off = 32; off; off >>= 1) m = fmaxf(m, __shfl_xor(m, off));
  float p = __expf(e - m);
  float ssum = p;
  #pragma unroll
  for (int off = 32; off; off >>= 1) ssum += __shfl_xor(ssum, off);
  float inv = 1.f / (ssum + 1e-16f);

  int g  = lane >> 3;            // edge group 0..7
  int sl = lane & 7;             // 16B slot in 128B row
  unsigned slb = (unsigned)sl * 16u;
  const char* hb = (const char*)hbf;
  float acc[8];
  #pragma unroll
  for (int i = 0; i < 8; ++i) acc[i] = 0.f;
  for (int i = 0; i < dg; i += 16){
    int jA = i + g, jB = i + 8 + g;
    int sA = __shfl(src_l, jA); float pA = __shfl(p, jA);
    int sB = __shfl(src_l, jB); float pB = __shfl(p, jB);
    if (jA >= dg){ pA = 0.f; sA = 0; }
    if (jB >= dg){ pB = 0.f; sB = 0; }
    uint4 vA = *(const uint4*)(hb + ((((unsigned)sA) << 7) | slb));
    uint4 vB = *(const uint4*)(hb + ((((unsigned)sB) << 7) | slb));
    FMA8(pA, vA)
    FMA8(pB, vB)
  }
  #pragma unroll
  for (int off = 8; off <= 32; off <<= 1){
    #pragma unroll
    for (int i = 0; i < 8; ++i) acc[i] += __shfl_xor(acc[i], off);
  }
  if (lane < 8){
    float4 b0 = ((const float4*)bias)[2 * sl];
    float4 b1 = ((const float4*)bias)[2 * sl + 1];
    float4 r0, r1;
    r0.x = acc[0] * inv + b0.x;
    r0.y = acc[1] * inv + b0.y;
    r0.z = acc[2] * inv + b0.z;
    r0.w = acc[3] * inv + b0.w;
    r1.x = acc[4] * inv + b1.x;
    r1.y = acc[5] * inv + b1.y;
    r1.z = acc[6] * inv + b1.z;
    r1.w = acc[7] * inv + b1.w;
    ((float4*)dout)[(size_t)w * 16 + 2 * sl]     = r0;
    ((float4*)dout)[(size_t)w * 16 + 2 * sl + 1] = r1;
  }
}

extern "C" void kernel_launch(void* const* d_in, const int* in_sizes, int n_in,
                              void* d_out, int out_size, void* d_ws, size_t ws_size,
                              hipStream_t stream) {
  const int*   x_ids    = (const int*)d_in[0];
  const int*   ei       = (const int*)d_in[1];
  const float* item_emb = (const float*)d_in[2];
  const float* W1       = (const float*)d_in[3];
  const float* att_src1 = (const float*)d_in[4];
  const float* att_dst1 = (const float*)d_in[5];
  const float* bias1    = (const float*)d_in[6];
  const float* W2       = (const float*)d_in[7];
  const float* att_src2 = (const float*)d_in[8];
  const float* att_dst2 = (const float*)d_in[9];
  const float* bias2    = (const float*)d_in[10];
  float* dout = (float*)d_out;

  int N  = in_sizes[0];
  int E  = in_sizes[1] / 2;
  int nbk  = (N + NBNODE - 1) / NBNODE;      // 782
  int nblk = (E + CHUNK - 1) / CHUNK;        // 391

  float* ws = (float*)d_ws;
  size_t o = 0;
  unsigned* h1bf = (unsigned*)(ws + o); o += (size_t)N * 64;   // layer1 lin rows (bf16x2)
  unsigned* h1p  = (unsigned*)(ws + o); o += (size_t)N * 64;   // layer1 output (bf16x2)
  unsigned* h2bf = (unsigned*)(ws + o); o += (size_t)N * 32;   // layer2 lin rows (bf16x2)
  float* a_src1 = ws + o; o += (size_t)N * 2;
  float* a_dst1 = ws + o; o += (size_t)N * 2;
  float* a_src2 = ws + o; o += N;
  float* a_dst2 = ws + o; o += N;
  int* deg  = (int*)(ws + o); o += N;
  int* csr  = (int*)(ws + o); o += (size_t)N * PAD;
  int* offs = (int*)(ws + o); o += (size_t)nblk * (nbk + 1);
  unsigned* ebuf = (unsigned*)(ws + o); o += E;

  int gL1 = (N + 31) / 32;                       // lin1 blocks needed
  int M   = (gL1 + nblk - 1) / nblk + 1;         // interleave period (1 sort : M-1 lin1)
  int G   = nblk * M;

  int gW  = (N + 3) / 4;
  int gL2 = (N + 31) / 32;

  k_bl1<<<G, 256, 0, stream>>>(ei, E, N, nbk, nblk, M, offs, ebuf,
        x_ids, item_emb, W1, att_src1, att_dst1, h1bf, a_src1, a_dst1);
  k_build<<<nbk, 256, 0, stream>>>(offs, ebuf, N, nbk, nblk, deg, csr);
  k_gat1<<<gW, 256, 0, stream>>>(deg, csr, a_src1, a_dst1, h1bf, bias1, h1p, N);
  k_lin2<<<gL2, 256, 0, stream>>>(h1p, W2, att_src2, att_dst2, h2bf, a_src2, a_dst2, N);
  k_gat2<<<gW, 256, 0, stream>>>(deg, csr, a_src2, a_dst2, h2bf, bias2, dout, N);
}

// Round 14
// 205.810 us; speedup vs baseline: 1.2184x; 1.2184x over previous
//
#include <hip/hip_runtime.h>
#include <hip/hip_bf16.h>

#define NEG_SLOPE 0.2f
#define PAD 64          // padded CSR row; slot 0 = self-loop, slots 1..63 = edges
#define NBNODE 128      // dst nodes per bucket
#define CHUNK 4096      // edges per sort block

typedef __attribute__((ext_vector_type(8))) short bf16x8;
typedef __attribute__((ext_vector_type(4))) float f32x4;

__device__ __forceinline__ float lrelu(float x){ return x >= 0.f ? x : NEG_SLOPE * x; }

__device__ __forceinline__ unsigned pack_bf16(float a, float b){
  unsigned ua = __float_as_uint(a), ub = __float_as_uint(b);
  ua = (ua + 0x7fffu + ((ua >> 16) & 1u)) >> 16;
  ub = (ub + 0x7fffu + ((ub >> 16) & 1u)) >> 16;
  return ua | (ub << 16);
}
__device__ __forceinline__ float bflo(unsigned u){ return __uint_as_float(u << 16); }
__device__ __forceinline__ float bfhi(unsigned u){ return __uint_as_float(u & 0xffff0000u); }

// ---------------- fused: chunk bucket-sort (no global atomics) + layer1 linear ----------------
__global__ __launch_bounds__(256) void k_bl1(const int* __restrict__ ei, int E, int N,
        int nbk, int nblk, int M,
        int* __restrict__ offs, unsigned* __restrict__ ebuf,
        const int* __restrict__ x_ids, const float* __restrict__ item_emb,
        const float* __restrict__ W1, const float* __restrict__ att_s, const float* __restrict__ att_d,
        unsigned* __restrict__ h1bf, float* __restrict__ a_src, float* __restrict__ a_dst){
  int b = blockIdx.x;
  int t = threadIdx.x;
  int lane = t & 63, wid = t >> 6;
  if (b % M == 0){
    int c = b / M;
    if (c >= nblk) return;
    __shared__ int lh[1024];     // histogram, then cursors
    __shared__ int st[1025];     // exclusive starts
    __shared__ int ws5[5];
    for (int i = t; i < nbk; i += 256) lh[i] = 0;
    __syncthreads();
    int ce = c * CHUNK;
    int cnt = E - ce; if (cnt > CHUNK) cnt = CHUNK;
    #pragma unroll
    for (int i = 0; i < 16; ++i){
      int e = t + i * 256;
      if (e < cnt){
        int d = ei[E + ce + e];
        atomicAdd(&lh[d >> 7], 1);
      }
    }
    __syncthreads();
    int idx0 = t * 4;
    int v0 = 0, v1 = 0, v2 = 0, v3 = 0;
    if (idx0     < nbk) v0 = lh[idx0];
    if (idx0 + 1 < nbk) v1 = lh[idx0 + 1];
    if (idx0 + 2 < nbk) v2 = lh[idx0 + 2];
    if (idx0 + 3 < nbk) v3 = lh[idx0 + 3];
    int ts = v0 + v1 + v2 + v3;
    int x = ts;
    #pragma unroll
    for (int off = 1; off < 64; off <<= 1){
      int y = __shfl_up(x, off);
      if (lane >= off) x += y;
    }
    if (lane == 63) ws5[wid] = x;
    __syncthreads();
    if (t == 0){
      int a = 0;
      #pragma unroll
      for (int k = 0; k < 4; ++k){ int tmp = ws5[k]; ws5[k] = a; a += tmp; }
      ws5[4] = a;
      st[nbk] = a;
    }
    __syncthreads();
    int ex = x - ts + ws5[wid];
    if (idx0     < nbk) st[idx0]     = ex;
    if (idx0 + 1 < nbk) st[idx0 + 1] = ex + v0;
    if (idx0 + 2 < nbk) st[idx0 + 2] = ex + v0 + v1;
    if (idx0 + 3 < nbk) st[idx0 + 3] = ex + v0 + v1 + v2;
    __syncthreads();
    for (int i = t; i < nbk; i += 256) lh[i] = st[i];          // cursors
    for (int i = t; i <= nbk; i += 256) offs[(size_t)c * (nbk + 1) + i] = st[i];
    __syncthreads();
    #pragma unroll
    for (int i = 0; i < 16; ++i){
      int e = t + i * 256;
      if (e < cnt){
        int s = ei[ce + e];
        int d = ei[E + ce + e];
        int r = atomicAdd(&lh[d >> 7], 1);
        ebuf[(size_t)ce + r] = (unsigned)s | ((unsigned)(d & 127) << 17);
      }
    }
    return;
  }
  // ---- lin1: W1 column-pair in registers, readlane broadcast, LDS-free ----
  int lid = (b / M) * (M - 1) + (b % M) - 1;
  int base = lid * 32 + wid * 8;
  if (base >= N) return;
  float2 w1c[32];
  const float2* W12 = (const float2*)W1;
  #pragma unroll
  for (int k = 0; k < 32; ++k) w1c[k] = W12[(k << 6) + lane];
  int c0 = 2 * lane;
  float as0 = att_s[c0], as1 = att_s[c0 + 1];
  float ad0 = att_d[c0], ad1 = att_d[c0 + 1];
  for (int it = 0; it < 8; ++it){
    int n = base + it;
    if (n >= N) break;
    float xv = 0.f;
    if (lane < 32){
      int id = x_ids[n];
      xv = (id == 0) ? 0.f : item_emb[(size_t)id * 32 + lane];
    }
    float acc0 = 0.f, acc1 = 0.f;
    #pragma unroll
    for (int k = 0; k < 32; ++k){
      float xk = __uint_as_float(__builtin_amdgcn_readlane(__float_as_uint(xv), k));
      acc0 += xk * w1c[k].x;
      acc1 += xk * w1c[k].y;
    }
    h1bf[(size_t)n * 64 + lane] = pack_bf16(acc0, acc1);
    float ps = acc0 * as0 + acc1 * as1;
    float pd = acc0 * ad0 + acc1 * ad1;
    #pragma unroll
    for (int off = 16; off; off >>= 1){
      ps += __shfl_xor(ps, off);
      pd += __shfl_xor(pd, off);
    }
    if ((lane & 31) == 0){
      int head = lane >> 5;
      a_src[n * 2 + head] = ps;
      a_dst[n * 2 + head] = pd;
    }
  }
}

// ---------------- per-bucket CSR build in LDS, coalesced global write ----------------
__global__ __launch_bounds__(256) void k_build(const int* __restrict__ offs,
        const unsigned* __restrict__ ebuf, int N, int nbk, int nblk,
        int* __restrict__ deg, int* __restrict__ csr){
  __shared__ int lcsr[NBNODE * PAD];   // 32 KB
  __shared__ int ldeg[NBNODE];
  int b = blockIdx.x, t = threadIdx.x;
  int base = b * NBNODE;
  int nn = N - base; if (nn > NBNODE) nn = NBNODE;
  for (int i = t; i < NBNODE; i += 256) ldeg[i] = 0;
  __syncthreads();
  for (int c = t; c < nblk; c += 256){
    size_t ob = (size_t)c * (nbk + 1) + b;
    int o0 = offs[ob];
    int o1 = offs[ob + 1];
    size_t ce = (size_t)c * CHUNK;
    for (int i = o0; i < o1; ++i){
      unsigned u = ebuf[ce + i];
      int ld = (int)(u >> 17);
      int s  = (int)(u & 0x1FFFFu);
      int slot = 1 + atomicAdd(&ldeg[ld], 1);
      if (slot < PAD) lcsr[(ld << 6) + slot] = s;
    }
  }
  __syncthreads();
  for (int i = t; i < nn; i += 256){
    int dv = ldeg[i];
    deg[base + i] = (dv > PAD - 1) ? (PAD - 1) : dv;
  }
  const uint4* l4 = (const uint4*)lcsr;
  uint4* g4 = (uint4*)(csr + ((size_t)base << 6));
  int n4 = nn * 16;
  for (int i = t; i < n4; i += 256) g4[i] = l4[i];
}

#define FMA8(P, V) \
  acc[0] += (P) * bflo((V).x); acc[1] += (P) * bfhi((V).x); \
  acc[2] += (P) * bflo((V).y); acc[3] += (P) * bfhi((V).y); \
  acc[4] += (P) * bflo((V).z); acc[5] += (P) * bfhi((V).z); \
  acc[6] += (P) * bflo((V).w); acc[7] += (P) * bfhi((V).w);

// ---------------- layer 1 fused attention + aggregation (bf16 rows in & out) ----------------
__global__ __launch_bounds__(256) void k_gat1(const int* __restrict__ deg, const int* __restrict__ csr,
        const float* __restrict__ a_src, const float* __restrict__ a_dst,
        const unsigned* __restrict__ hbf, const float* __restrict__ bias,
        unsigned* __restrict__ h1p, int N){
  int w = blockIdx.x * 4 + (threadIdx.x >> 6);
  int lane = threadIdx.x & 63;
  if (w >= N) return;
  int cnt = deg[w]; if (cnt > PAD - 1) cnt = PAD - 1;
  int dg = cnt + 1;
  int src_l = (lane == 0) ? w : csr[((size_t)w << 6) + lane];
  float2 ad = ((const float2*)a_dst)[w];
  float e0 = -__builtin_inff(), e1 = -__builtin_inff();
  if (lane < dg){
    float2 as = ((const float2*)a_src)[src_l];
    e0 = lrelu(as.x + ad.x);
    e1 = lrelu(as.y + ad.y);
  }
  float m0 = e0, m1 = e1;
  #pragma unroll
  for (int off = 32; off; off >>= 1){
    m0 = fmaxf(m0, __shfl_xor(m0, off));
    m1 = fmaxf(m1, __shfl_xor(m1, off));
  }
  float p0 = __expf(e0 - m0);
  float p1 = __expf(e1 - m1);
  float s0 = p0, s1 = p1;
  #pragma unroll
  for (int off = 32; off; off >>= 1){
    s0 += __shfl_xor(s0, off);
    s1 += __shfl_xor(s1, off);
  }
  float inv0 = 1.f / (s0 + 1e-16f);
  float inv1 = 1.f / (s1 + 1e-16f);
  unsigned ppk = pack_bf16(p0, p1);       // bf16 pair for one-shfl broadcast

  int g  = lane >> 4;            // edge group 0..3
  int sl = lane & 15;            // 16B slot in 256B row
  unsigned slb = (unsigned)sl * 16u;
  const char* hb = (const char*)hbf;
  float acc[8];
  #pragma unroll
  for (int i = 0; i < 8; ++i) acc[i] = 0.f;
  for (int i = 0; i < dg; i += 16){
    int jA = i + g, jB = i + 4 + g, jC = i + 8 + g, jD = i + 12 + g;
    int sA = __shfl(src_l, jA); unsigned kA = (unsigned)__shfl((int)ppk, jA);
    int sB = __shfl(src_l, jB); unsigned kB = (unsigned)__shfl((int)ppk, jB);
    int sC = __shfl(src_l, jC); unsigned kC = (unsigned)__shfl((int)ppk, jC);
    int sD = __shfl(src_l, jD); unsigned kD = (unsigned)__shfl((int)ppk, jD);
    float pA = (sl < 8) ? bflo(kA) : bfhi(kA); if (jA >= dg){ pA = 0.f; sA = 0; }
    float pB = (sl < 8) ? bflo(kB) : bfhi(kB); if (jB >= dg){ pB = 0.f; sB = 0; }
    float pC = (sl < 8) ? bflo(kC) : bfhi(kC); if (jC >= dg){ pC = 0.f; sC = 0; }
    float pD = (sl < 8) ? bflo(kD) : bfhi(kD); if (jD >= dg){ pD = 0.f; sD = 0; }
    uint4 vA = *(const uint4*)(hb + ((((unsigned)sA) << 8) | slb));
    uint4 vB = *(const uint4*)(hb + ((((unsigned)sB) << 8) | slb));
    uint4 vC = *(const uint4*)(hb + ((((unsigned)sC) << 8) | slb));
    uint4 vD = *(const uint4*)(hb + ((((unsigned)sD) << 8) | slb));
    FMA8(pA, vA)
    FMA8(pB, vB)
    FMA8(pC, vC)
    FMA8(pD, vD)
  }
  #pragma unroll
  for (int off = 16; off <= 32; off <<= 1){
    #pragma unroll
    for (int i = 0; i < 8; ++i) acc[i] += __shfl_xor(acc[i], off);
  }
  if (lane < 16){
    float inv = (sl < 8) ? inv0 : inv1;
    float4 b0 = ((const float4*)bias)[2 * sl];
    float4 b1 = ((const float4*)bias)[2 * sl + 1];
    float r0 = fmaxf(acc[0] * inv + b0.x, 0.f);
    float r1 = fmaxf(acc[1] * inv + b0.y, 0.f);
    float r2 = fmaxf(acc[2] * inv + b0.z, 0.f);
    float r3 = fmaxf(acc[3] * inv + b0.w, 0.f);
    float r4 = fmaxf(acc[4] * inv + b1.x, 0.f);
    float r5 = fmaxf(acc[5] * inv + b1.y, 0.f);
    float r6 = fmaxf(acc[6] * inv + b1.z, 0.f);
    float r7 = fmaxf(acc[7] * inv + b1.w, 0.f);
    uint4 pk;
    pk.x = pack_bf16(r0, r1);
    pk.y = pack_bf16(r2, r3);
    pk.z = pack_bf16(r4, r5);
    pk.w = pack_bf16(r6, r7);
    ((uint4*)h1p)[(size_t)w * 16 + sl] = pk;
  }
}

// ---------------- layer 2 linear via MFMA + attention dots ----------------
// wave per 16-node tile; A = h1p rows (bf16, already fragment-layout), B = W2 (bf16 regs).
// mfma_f32_16x16x32_bf16: A lane l: row=l&15, k=(l>>4)*8+j. B: col=l&15, k likewise.
// C: col=lane&15, row=(lane>>4)*4+reg (verified mapping).
__global__ __launch_bounds__(256) void k_lin2m(const unsigned* __restrict__ h1p,
        const float* __restrict__ W2, const float* __restrict__ att_s, const float* __restrict__ att_d,
        unsigned* __restrict__ h2bf, float* __restrict__ a_src, float* __restrict__ a_dst,
        int N, int ntile){
  int wid = threadIdx.x >> 6, lane = threadIdx.x & 63;
  int tile = blockIdx.x * 4 + wid;
  if (tile >= ntile) return;
  int col16 = lane & 15, grp = lane >> 4;
  // B fragments: bf[kk][ct] covers k in [32kk,32kk+32), cols [16ct,16ct+16)
  bf16x8 bfr[4][4];
  #pragma unroll
  for (int kk = 0; kk < 4; ++kk){
    int kbase = kk * 32 + grp * 8;
    #pragma unroll
    for (int ct = 0; ct < 4; ++ct){
      int col = ct * 16 + col16;
      union { unsigned u[4]; bf16x8 v; } cv;
      #pragma unroll
      for (int jj = 0; jj < 4; ++jj){
        float w0 = W2[(size_t)(kbase + 2 * jj) * 64 + col];
        float w1 = W2[(size_t)(kbase + 2 * jj + 1) * 64 + col];
        cv.u[jj] = pack_bf16(w0, w1);
      }
      bfr[kk][ct] = cv.v;
    }
  }
  int row = tile * 16 + col16;
  int arow = (row < N) ? row : N - 1;      // clamp OOB rows (stores guarded)
  const uint4* hp = (const uint4*)h1p;
  f32x4 cc[4];
  #pragma unroll
  for (int ct = 0; ct < 4; ++ct) cc[ct] = (f32x4){0.f, 0.f, 0.f, 0.f};
  #pragma unroll
  for (int kk = 0; kk < 4; ++kk){
    union { uint4 u; bf16x8 v; } ac;
    ac.u = hp[(size_t)arow * 16 + kk * 4 + grp];
    cc[0] = __builtin_amdgcn_mfma_f32_16x16x32_bf16(ac.v, bfr[kk][0], cc[0], 0, 0, 0);
    cc[1] = __builtin_amdgcn_mfma_f32_16x16x32_bf16(ac.v, bfr[kk][1], cc[1], 0, 0, 0);
    cc[2] = __builtin_amdgcn_mfma_f32_16x16x32_bf16(ac.v, bfr[kk][2], cc[2], 0, 0, 0);
    cc[3] = __builtin_amdgcn_mfma_f32_16x16x32_bf16(ac.v, bfr[kk][3], cc[3], 0, 0, 0);
  }
  // attention dots: row n -> sum_c h2[n][c]*att[c]; reduce across 16 cols per group
  float dsv[4] = {0.f, 0.f, 0.f, 0.f}, ddv[4] = {0.f, 0.f, 0.f, 0.f};
  #pragma unroll
  for (int ct = 0; ct < 4; ++ct){
    float asc = att_s[ct * 16 + col16];
    float adc = att_d[ct * 16 + col16];
    #pragma unroll
    for (int r = 0; r < 4; ++r){
      dsv[r] += cc[ct][r] * asc;
      ddv[r] += cc[ct][r] * adc;
    }
  }
  #pragma unroll
  for (int off = 1; off <= 8; off <<= 1){
    #pragma unroll
    for (int r = 0; r < 4; ++r){
      dsv[r] += __shfl_xor(dsv[r], off);
      ddv[r] += __shfl_xor(ddv[r], off);
    }
  }
  if (col16 == 0){
    #pragma unroll
    for (int r = 0; r < 4; ++r){
      int n = tile * 16 + grp * 4 + r;
      if (n < N){ a_src[n] = dsv[r]; a_dst[n] = ddv[r]; }
    }
  }
  // h2bf store: pair adjacent cols via shfl, even lanes write packed uint
  #pragma unroll
  for (int ct = 0; ct < 4; ++ct){
    #pragma unroll
    for (int r = 0; r < 4; ++r){
      float own = cc[ct][r];
      float pr  = __shfl_xor(own, 1);
      if (!(lane & 1)){
        int n = tile * 16 + grp * 4 + r;
        if (n < N)
          h2bf[(size_t)n * 32 + ct * 8 + (col16 >> 1)] = pack_bf16(own, pr);
      }
    }
  }
}

// ---------------- layer 2 fused attention + aggregation (bf16 rows) ----------------
__global__ __launch_bounds__(256) void k_gat2(const int* __restrict__ deg, const int* __restrict__ csr,
        const float* __restrict__ a_src, const float* __restrict__ a_dst,
        const unsigned* __restrict__ hbf, const float* __restrict__ bias,
        float* __restrict__ dout, int N){
  int w = blockIdx.x * 4 + (threadIdx.x >> 6);
  int lane = threadIdx.x & 63;
  if (w >= N) return;
  int cnt = deg[w]; if (cnt > PAD - 1) cnt = PAD - 1;
  int dg = cnt + 1;
  int src_l = (lane == 0) ? w : csr[((size_t)w << 6) + lane];
  float ad = a_dst[w];
  float e = -__builtin_inff();
  if (lane < dg) e = lrelu(a_src[src_l] + ad);
  float m = e;
  #pragma unroll
  for (int off = 32; off; off >>= 1) m = fmaxf(m, __shfl_xor(m, off));
  float p = __expf(e - m);
  float ssum = p;
  #pragma unroll
  for (int off = 32; off; off >>= 1) ssum += __shfl_xor(ssum, off);
  float inv = 1.f / (ssum + 1e-16f);

  int g  = lane >> 3;            // edge group 0..7
  int sl = lane & 7;             // 16B slot in 128B row
  unsigned slb = (unsigned)sl * 16u;
  const char* hb = (const char*)hbf;
  float acc[8];
  #pragma unroll
  for (int i = 0; i < 8; ++i) acc[i] = 0.f;
  for (int i = 0; i < dg; i += 16){
    int jA = i + g, jB = i + 8 + g;
    int sA = __shfl(src_l, jA); float pA = __shfl(p, jA);
    int sB = __shfl(src_l, jB); float pB = __shfl(p, jB);
    if (jA >= dg){ pA = 0.f; sA = 0; }
    if (jB >= dg){ pB = 0.f; sB = 0; }
    uint4 vA = *(const uint4*)(hb + ((((unsigned)sA) << 7) | slb));
    uint4 vB = *(const uint4*)(hb + ((((unsigned)sB) << 7) | slb));
    FMA8(pA, vA)
    FMA8(pB, vB)
  }
  #pragma unroll
  for (int off = 8; off <= 32; off <<= 1){
    #pragma unroll
    for (int i = 0; i < 8; ++i) acc[i] += __shfl_xor(acc[i], off);
  }
  if (lane < 8){
    float4 b0 = ((const float4*)bias)[2 * sl];
    float4 b1 = ((const float4*)bias)[2 * sl + 1];
    float4 r0, r1;
    r0.x = acc[0] * inv + b0.x;
    r0.y = acc[1] * inv + b0.y;
    r0.z = acc[2] * inv + b0.z;
    r0.w = acc[3] * inv + b0.w;
    r1.x = acc[4] * inv + b1.x;
    r1.y = acc[5] * inv + b1.y;
    r1.z = acc[6] * inv + b1.z;
    r1.w = acc[7] * inv + b1.w;
    ((float4*)dout)[(size_t)w * 16 + 2 * sl]     = r0;
    ((float4*)dout)[(size_t)w * 16 + 2 * sl + 1] = r1;
  }
}

extern "C" void kernel_launch(void* const* d_in, const int* in_sizes, int n_in,
                              void* d_out, int out_size, void* d_ws, size_t ws_size,
                              hipStream_t stream) {
  const int*   x_ids    = (const int*)d_in[0];
  const int*   ei       = (const int*)d_in[1];
  const float* item_emb = (const float*)d_in[2];
  const float* W1       = (const float*)d_in[3];
  const float* att_src1 = (const float*)d_in[4];
  const float* att_dst1 = (const float*)d_in[5];
  const float* bias1    = (const float*)d_in[6];
  const float* W2       = (const float*)d_in[7];
  const float* att_src2 = (const float*)d_in[8];
  const float* att_dst2 = (const float*)d_in[9];
  const float* bias2    = (const float*)d_in[10];
  float* dout = (float*)d_out;

  int N  = in_sizes[0];
  int E  = in_sizes[1] / 2;
  int nbk  = (N + NBNODE - 1) / NBNODE;      // 782
  int nblk = (E + CHUNK - 1) / CHUNK;        // 391

  float* ws = (float*)d_ws;
  size_t o = 0;
  unsigned* h1bf = (unsigned*)(ws + o); o += (size_t)N * 64;   // layer1 lin rows (bf16x2)
  unsigned* h1p  = (unsigned*)(ws + o); o += (size_t)N * 64;   // layer1 output (bf16x2)
  unsigned* h2bf = (unsigned*)(ws + o); o += (size_t)N * 32;   // layer2 lin rows (bf16x2)
  float* a_src1 = ws + o; o += (size_t)N * 2;
  float* a_dst1 = ws + o; o += (size_t)N * 2;
  float* a_src2 = ws + o; o += N;
  float* a_dst2 = ws + o; o += N;
  int* deg  = (int*)(ws + o); o += N;
  int* csr  = (int*)(ws + o); o += (size_t)N * PAD;
  int* offs = (int*)(ws + o); o += (size_t)nblk * (nbk + 1);
  unsigned* ebuf = (unsigned*)(ws + o); o += E;

  int gL1 = (N + 31) / 32;                       // lin1 blocks needed
  int M   = (gL1 + nblk - 1) / nblk + 1;         // interleave period (1 sort : M-1 lin1)
  int G   = nblk * M;

  int gW    = (N + 3) / 4;
  int ntile = (N + 15) / 16;
  int gL2m  = (ntile + 3) / 4;

  k_bl1<<<G, 256, 0, stream>>>(ei, E, N, nbk, nblk, M, offs, ebuf,
        x_ids, item_emb, W1, att_src1, att_dst1, h1bf, a_src1, a_dst1);
  k_build<<<nbk, 256, 0, stream>>>(offs, ebuf, N, nbk, nblk, deg, csr);
  k_gat1<<<gW, 256, 0, stream>>>(deg, csr, a_src1, a_dst1, h1bf, bias1, h1p, N);
  k_lin2m<<<gL2m, 256, 0, stream>>>(h1p, W2, att_src2, att_dst2, h2bf, a_src2, a_dst2, N, ntile);
  k_gat2<<<gW, 256, 0, stream>>>(deg, csr, a_src2, a_dst2, h2bf, bias2, dout, N);
}

// Round 15
// 202.972 us; speedup vs baseline: 1.2354x; 1.0140x over previous
//
#include <hip/hip_runtime.h>
#include <hip/hip_bf16.h>

#define NEG_SLOPE 0.2f
#define PAD 64          // padded CSR row; slot 0 = self-loop, slots 1..63 = edges
#define NBNODE 128      // dst nodes per bucket
#define CHUNK 4096      // edges per sort block

typedef __attribute__((ext_vector_type(8))) short bf16x8;
typedef __attribute__((ext_vector_type(4))) float f32x4;

__device__ __forceinline__ float lrelu(float x){ return x >= 0.f ? x : NEG_SLOPE * x; }

__device__ __forceinline__ unsigned pack_bf16(float a, float b){
  unsigned ua = __float_as_uint(a), ub = __float_as_uint(b);
  ua = (ua + 0x7fffu + ((ua >> 16) & 1u)) >> 16;
  ub = (ub + 0x7fffu + ((ub >> 16) & 1u)) >> 16;
  return ua | (ub << 16);
}
__device__ __forceinline__ float bflo(unsigned u){ return __uint_as_float(u << 16); }
__device__ __forceinline__ float bfhi(unsigned u){ return __uint_as_float(u & 0xffff0000u); }

// ---------------- fused: chunk bucket-sort (no global atomics) + layer1 linear ----------------
__global__ __launch_bounds__(256) void k_bl1(const int* __restrict__ ei, int E, int N,
        int nbk, int nblk, int M,
        int* __restrict__ offs, unsigned* __restrict__ ebuf,
        const int* __restrict__ x_ids, const float* __restrict__ item_emb,
        const float* __restrict__ W1, const float* __restrict__ att_s, const float* __restrict__ att_d,
        unsigned* __restrict__ h1bf, float* __restrict__ a_src, float* __restrict__ a_dst){
  int b = blockIdx.x;
  int t = threadIdx.x;
  int lane = t & 63, wid = t >> 6;
  if (b % M == 0){
    int c = b / M;
    if (c >= nblk) return;
    __shared__ int lh[1024];     // histogram, then cursors
    __shared__ int st[1025];     // exclusive starts
    __shared__ int ws5[5];
    for (int i = t; i < nbk; i += 256) lh[i] = 0;
    __syncthreads();
    int ce = c * CHUNK;
    int cnt = E - ce; if (cnt > CHUNK) cnt = CHUNK;
    #pragma unroll
    for (int i = 0; i < 16; ++i){
      int e = t + i * 256;
      if (e < cnt){
        int d = ei[E + ce + e];
        atomicAdd(&lh[d >> 7], 1);
      }
    }
    __syncthreads();
    int idx0 = t * 4;
    int v0 = 0, v1 = 0, v2 = 0, v3 = 0;
    if (idx0     < nbk) v0 = lh[idx0];
    if (idx0 + 1 < nbk) v1 = lh[idx0 + 1];
    if (idx0 + 2 < nbk) v2 = lh[idx0 + 2];
    if (idx0 + 3 < nbk) v3 = lh[idx0 + 3];
    int ts = v0 + v1 + v2 + v3;
    int x = ts;
    #pragma unroll
    for (int off = 1; off < 64; off <<= 1){
      int y = __shfl_up(x, off);
      if (lane >= off) x += y;
    }
    if (lane == 63) ws5[wid] = x;
    __syncthreads();
    if (t == 0){
      int a = 0;
      #pragma unroll
      for (int k = 0; k < 4; ++k){ int tmp = ws5[k]; ws5[k] = a; a += tmp; }
      ws5[4] = a;
      st[nbk] = a;
    }
    __syncthreads();
    int ex = x - ts + ws5[wid];
    if (idx0     < nbk) st[idx0]     = ex;
    if (idx0 + 1 < nbk) st[idx0 + 1] = ex + v0;
    if (idx0 + 2 < nbk) st[idx0 + 2] = ex + v0 + v1;
    if (idx0 + 3 < nbk) st[idx0 + 3] = ex + v0 + v1 + v2;
    __syncthreads();
    for (int i = t; i < nbk; i += 256) lh[i] = st[i];          // cursors
    for (int i = t; i <= nbk; i += 256) offs[(size_t)c * (nbk + 1) + i] = st[i];
    __syncthreads();
    #pragma unroll
    for (int i = 0; i < 16; ++i){
      int e = t + i * 256;
      if (e < cnt){
        int s = ei[ce + e];
        int d = ei[E + ce + e];
        int r = atomicAdd(&lh[d >> 7], 1);
        ebuf[(size_t)ce + r] = (unsigned)s | ((unsigned)(d & 127) << 17);
      }
    }
    return;
  }
  // ---- lin1: W1 column-pair in registers, readlane broadcast, LDS-free ----
  int lid = (b / M) * (M - 1) + (b % M) - 1;
  int base = lid * 32 + wid * 8;
  if (base >= N) return;
  float2 w1c[32];
  const float2* W12 = (const float2*)W1;
  #pragma unroll
  for (int k = 0; k < 32; ++k) w1c[k] = W12[(k << 6) + lane];
  int c0 = 2 * lane;
  float as0 = att_s[c0], as1 = att_s[c0 + 1];
  float ad0 = att_d[c0], ad1 = att_d[c0 + 1];
  for (int it = 0; it < 8; ++it){
    int n = base + it;
    if (n >= N) break;
    float xv = 0.f;
    if (lane < 32){
      int id = x_ids[n];
      xv = (id == 0) ? 0.f : item_emb[(size_t)id * 32 + lane];
    }
    float acc0 = 0.f, acc1 = 0.f;
    #pragma unroll
    for (int k = 0; k < 32; ++k){
      float xk = __uint_as_float(__builtin_amdgcn_readlane(__float_as_uint(xv), k));
      acc0 += xk * w1c[k].x;
      acc1 += xk * w1c[k].y;
    }
    h1bf[(size_t)n * 64 + lane] = pack_bf16(acc0, acc1);
    float ps = acc0 * as0 + acc1 * as1;
    float pd = acc0 * ad0 + acc1 * ad1;
    #pragma unroll
    for (int off = 16; off; off >>= 1){
      ps += __shfl_xor(ps, off);
      pd += __shfl_xor(pd, off);
    }
    if ((lane & 31) == 0){
      int head = lane >> 5;
      a_src[n * 2 + head] = ps;
      a_dst[n * 2 + head] = pd;
    }
  }
}

// ---------------- per-bucket CSR build in LDS + W2 fragment pre-pack (last block) ----------------
__global__ __launch_bounds__(256) void k_build(const int* __restrict__ offs,
        const unsigned* __restrict__ ebuf, int N, int nbk, int nblk,
        int* __restrict__ deg, int* __restrict__ csr,
        const float* __restrict__ W2, unsigned* __restrict__ w2p){
  int b = blockIdx.x, t = threadIdx.x;
  if (b == nbk){
    // pack W2 into MFMA B-fragment layout: w2p[(kk*4+ct)*64 + lane] = uint4 of 4 k-pair bf16 packs
    for (int idx = t; idx < 1024; idx += 256){
      int kkct = idx >> 6, ln = idx & 63;
      int kk = kkct >> 2, ct = kkct & 3;
      int grp = ln >> 4, col16 = ln & 15;
      int kbase = kk * 32 + grp * 8;
      int col = ct * 16 + col16;
      uint4 v;
      v.x = pack_bf16(W2[(size_t)(kbase + 0) * 64 + col], W2[(size_t)(kbase + 1) * 64 + col]);
      v.y = pack_bf16(W2[(size_t)(kbase + 2) * 64 + col], W2[(size_t)(kbase + 3) * 64 + col]);
      v.z = pack_bf16(W2[(size_t)(kbase + 4) * 64 + col], W2[(size_t)(kbase + 5) * 64 + col]);
      v.w = pack_bf16(W2[(size_t)(kbase + 6) * 64 + col], W2[(size_t)(kbase + 7) * 64 + col]);
      ((uint4*)w2p)[idx] = v;
    }
    return;
  }
  __shared__ int lcsr[NBNODE * PAD];   // 32 KB
  __shared__ int ldeg[NBNODE];
  int base = b * NBNODE;
  int nn = N - base; if (nn > NBNODE) nn = NBNODE;
  for (int i = t; i < NBNODE; i += 256) ldeg[i] = 0;
  __syncthreads();
  for (int c = t; c < nblk; c += 256){
    size_t ob = (size_t)c * (nbk + 1) + b;
    int o0 = offs[ob];
    int o1 = offs[ob + 1];
    size_t ce = (size_t)c * CHUNK;
    for (int i = o0; i < o1; ++i){
      unsigned u = ebuf[ce + i];
      int ld = (int)(u >> 17);
      int s  = (int)(u & 0x1FFFFu);
      int slot = 1 + atomicAdd(&ldeg[ld], 1);
      if (slot < PAD) lcsr[(ld << 6) + slot] = s;
    }
  }
  __syncthreads();
  for (int i = t; i < nn; i += 256){
    int dv = ldeg[i];
    deg[base + i] = (dv > PAD - 1) ? (PAD - 1) : dv;
  }
  const uint4* l4 = (const uint4*)lcsr;
  uint4* g4 = (uint4*)(csr + ((size_t)base << 6));
  int n4 = nn * 16;
  for (int i = t; i < n4; i += 256) g4[i] = l4[i];
}

#define FMA8(P, V) \
  acc[0] += (P) * bflo((V).x); acc[1] += (P) * bfhi((V).x); \
  acc[2] += (P) * bflo((V).y); acc[3] += (P) * bfhi((V).y); \
  acc[4] += (P) * bflo((V).z); acc[5] += (P) * bfhi((V).z); \
  acc[6] += (P) * bflo((V).w); acc[7] += (P) * bfhi((V).w);

// ---------------- layer 1 fused attention + aggregation (bf16 rows in & out) ----------------
__global__ __launch_bounds__(256) void k_gat1(const int* __restrict__ deg, const int* __restrict__ csr,
        const float* __restrict__ a_src, const float* __restrict__ a_dst,
        const unsigned* __restrict__ hbf, const float* __restrict__ bias,
        unsigned* __restrict__ h1p, int N){
  int w = blockIdx.x * 4 + (threadIdx.x >> 6);
  int lane = threadIdx.x & 63;
  if (w >= N) return;
  int cnt = deg[w]; if (cnt > PAD - 1) cnt = PAD - 1;
  int dg = cnt + 1;
  int src_l = (lane == 0) ? w : csr[((size_t)w << 6) + lane];
  float2 ad = ((const float2*)a_dst)[w];
  float e0 = -__builtin_inff(), e1 = -__builtin_inff();
  if (lane < dg){
    float2 as = ((const float2*)a_src)[src_l];
    e0 = lrelu(as.x + ad.x);
    e1 = lrelu(as.y + ad.y);
  }
  float m0 = e0, m1 = e1;
  #pragma unroll
  for (int off = 32; off; off >>= 1){
    m0 = fmaxf(m0, __shfl_xor(m0, off));
    m1 = fmaxf(m1, __shfl_xor(m1, off));
  }
  float p0 = __expf(e0 - m0);
  float p1 = __expf(e1 - m1);
  float s0 = p0, s1 = p1;
  #pragma unroll
  for (int off = 32; off; off >>= 1){
    s0 += __shfl_xor(s0, off);
    s1 += __shfl_xor(s1, off);
  }
  float inv0 = 1.f / (s0 + 1e-16f);
  float inv1 = 1.f / (s1 + 1e-16f);
  unsigned ppk = pack_bf16(p0, p1);       // bf16 pair for one-shfl broadcast

  int g  = lane >> 4;            // edge group 0..3
  int sl = lane & 15;            // 16B slot in 256B row
  unsigned slb = (unsigned)sl * 16u;
  const char* hb = (const char*)hbf;
  float acc[8];
  #pragma unroll
  for (int i = 0; i < 8; ++i) acc[i] = 0.f;
  for (int i = 0; i < dg; i += 16){
    int jA = i + g, jB = i + 4 + g, jC = i + 8 + g, jD = i + 12 + g;
    int sA = __shfl(src_l, jA); unsigned kA = (unsigned)__shfl((int)ppk, jA);
    int sB = __shfl(src_l, jB); unsigned kB = (unsigned)__shfl((int)ppk, jB);
    int sC = __shfl(src_l, jC); unsigned kC = (unsigned)__shfl((int)ppk, jC);
    int sD = __shfl(src_l, jD); unsigned kD = (unsigned)__shfl((int)ppk, jD);
    float pA = (sl < 8) ? bflo(kA) : bfhi(kA); if (jA >= dg){ pA = 0.f; sA = 0; }
    float pB = (sl < 8) ? bflo(kB) : bfhi(kB); if (jB >= dg){ pB = 0.f; sB = 0; }
    float pC = (sl < 8) ? bflo(kC) : bfhi(kC); if (jC >= dg){ pC = 0.f; sC = 0; }
    float pD = (sl < 8) ? bflo(kD) : bfhi(kD); if (jD >= dg){ pD = 0.f; sD = 0; }
    uint4 vA = *(const uint4*)(hb + ((((unsigned)sA) << 8) | slb));
    uint4 vB = *(const uint4*)(hb + ((((unsigned)sB) << 8) | slb));
    uint4 vC = *(const uint4*)(hb + ((((unsigned)sC) << 8) | slb));
    uint4 vD = *(const uint4*)(hb + ((((unsigned)sD) << 8) | slb));
    FMA8(pA, vA)
    FMA8(pB, vB)
    FMA8(pC, vC)
    FMA8(pD, vD)
  }
  #pragma unroll
  for (int off = 16; off <= 32; off <<= 1){
    #pragma unroll
    for (int i = 0; i < 8; ++i) acc[i] += __shfl_xor(acc[i], off);
  }
  if (lane < 16){
    float inv = (sl < 8) ? inv0 : inv1;
    float4 b0 = ((const float4*)bias)[2 * sl];
    float4 b1 = ((const float4*)bias)[2 * sl + 1];
    float r0 = fmaxf(acc[0] * inv + b0.x, 0.f);
    float r1 = fmaxf(acc[1] * inv + b0.y, 0.f);
    float r2 = fmaxf(acc[2] * inv + b0.z, 0.f);
    float r3 = fmaxf(acc[3] * inv + b0.w, 0.f);
    float r4 = fmaxf(acc[4] * inv + b1.x, 0.f);
    float r5 = fmaxf(acc[5] * inv + b1.y, 0.f);
    float r6 = fmaxf(acc[6] * inv + b1.z, 0.f);
    float r7 = fmaxf(acc[7] * inv + b1.w, 0.f);
    uint4 pk;
    pk.x = pack_bf16(r0, r1);
    pk.y = pack_bf16(r2, r3);
    pk.z = pack_bf16(r4, r5);
    pk.w = pack_bf16(r6, r7);
    ((uint4*)h1p)[(size_t)w * 16 + sl] = pk;
  }
}

// ---------------- layer 2 linear via MFMA + attention dots ----------------
// wave per 2 16-node tiles; B-fragments loaded from pre-packed w2p (16 coalesced uint4).
__global__ __launch_bounds__(256) void k_lin2m(const unsigned* __restrict__ h1p,
        const unsigned* __restrict__ w2p, const float* __restrict__ att_s, const float* __restrict__ att_d,
        unsigned* __restrict__ h2bf, float* __restrict__ a_src, float* __restrict__ a_dst,
        int N, int ntile){
  int wid = threadIdx.x >> 6, lane = threadIdx.x & 63;
  int col16 = lane & 15, grp = lane >> 4;
  bf16x8 bfr[4][4];
  const uint4* wp4 = (const uint4*)w2p;
  #pragma unroll
  for (int kk = 0; kk < 4; ++kk){
    #pragma unroll
    for (int ct = 0; ct < 4; ++ct){
      union { uint4 u; bf16x8 v; } cv;
      cv.u = wp4[(kk * 4 + ct) * 64 + lane];
      bfr[kk][ct] = cv.v;
    }
  }
  const uint4* hp = (const uint4*)h1p;
  #pragma unroll
  for (int tt = 0; tt < 2; ++tt){
    int tile = (blockIdx.x * 4 + wid) * 2 + tt;
    if (tile >= ntile) return;
    int row = tile * 16 + col16;
    int arow = (row < N) ? row : N - 1;      // clamp OOB rows (stores guarded)
    f32x4 cc[4];
    #pragma unroll
    for (int ct = 0; ct < 4; ++ct) cc[ct] = (f32x4){0.f, 0.f, 0.f, 0.f};
    #pragma unroll
    for (int kk = 0; kk < 4; ++kk){
      union { uint4 u; bf16x8 v; } ac;
      ac.u = hp[(size_t)arow * 16 + kk * 4 + grp];
      cc[0] = __builtin_amdgcn_mfma_f32_16x16x32_bf16(ac.v, bfr[kk][0], cc[0], 0, 0, 0);
      cc[1] = __builtin_amdgcn_mfma_f32_16x16x32_bf16(ac.v, bfr[kk][1], cc[1], 0, 0, 0);
      cc[2] = __builtin_amdgcn_mfma_f32_16x16x32_bf16(ac.v, bfr[kk][2], cc[2], 0, 0, 0);
      cc[3] = __builtin_amdgcn_mfma_f32_16x16x32_bf16(ac.v, bfr[kk][3], cc[3], 0, 0, 0);
    }
    float dsv[4] = {0.f, 0.f, 0.f, 0.f}, ddv[4] = {0.f, 0.f, 0.f, 0.f};
    #pragma unroll
    for (int ct = 0; ct < 4; ++ct){
      float asc = att_s[ct * 16 + col16];
      float adc = att_d[ct * 16 + col16];
      #pragma unroll
      for (int r = 0; r < 4; ++r){
        dsv[r] += cc[ct][r] * asc;
        ddv[r] += cc[ct][r] * adc;
      }
    }
    #pragma unroll
    for (int off = 1; off <= 8; off <<= 1){
      #pragma unroll
      for (int r = 0; r < 4; ++r){
        dsv[r] += __shfl_xor(dsv[r], off);
        ddv[r] += __shfl_xor(ddv[r], off);
      }
    }
    if (col16 == 0){
      #pragma unroll
      for (int r = 0; r < 4; ++r){
        int n = tile * 16 + grp * 4 + r;
        if (n < N){ a_src[n] = dsv[r]; a_dst[n] = ddv[r]; }
      }
    }
    #pragma unroll
    for (int ct = 0; ct < 4; ++ct){
      #pragma unroll
      for (int r = 0; r < 4; ++r){
        float own = cc[ct][r];
        float pr  = __shfl_xor(own, 1);
        if (!(lane & 1)){
          int n = tile * 16 + grp * 4 + r;
          if (n < N)
            h2bf[(size_t)n * 32 + ct * 8 + (col16 >> 1)] = pack_bf16(own, pr);
        }
      }
    }
  }
}

// ---------------- layer 2 fused attention + aggregation (bf16 rows) ----------------
__global__ __launch_bounds__(256) void k_gat2(const int* __restrict__ deg, const int* __restrict__ csr,
        const float* __restrict__ a_src, const float* __restrict__ a_dst,
        const unsigned* __restrict__ hbf, const float* __restrict__ bias,
        float* __restrict__ dout, int N){
  int w = blockIdx.x * 4 + (threadIdx.x >> 6);
  int lane = threadIdx.x & 63;
  if (w >= N) return;
  int cnt = deg[w]; if (cnt > PAD - 1) cnt = PAD - 1;
  int dg = cnt + 1;
  int src_l = (lane == 0) ? w : csr[((size_t)w << 6) + lane];
  float ad = a_dst[w];
  float e = -__builtin_inff();
  if (lane < dg) e = lrelu(a_src[src_l] + ad);
  float m = e;
  #pragma unroll
  for (int off = 32; off; off >>= 1) m = fmaxf(m, __shfl_xor(m, off));
  float p = __expf(e - m);
  float ssum = p;
  #pragma unroll
  for (int off = 32; off; off >>= 1) ssum += __shfl_xor(ssum, off);
  float inv = 1.f / (ssum + 1e-16f);

  int g  = lane >> 3;            // edge group 0..7
  int sl = lane & 7;             // 16B slot in 128B row
  unsigned slb = (unsigned)sl * 16u;
  const char* hb = (const char*)hbf;
  float acc[8];
  #pragma unroll
  for (int i = 0; i < 8; ++i) acc[i] = 0.f;
  for (int i = 0; i < dg; i += 16){
    int jA = i + g, jB = i + 8 + g;
    int sA = __shfl(src_l, jA); float pA = __shfl(p, jA);
    int sB = __shfl(src_l, jB); float pB = __shfl(p, jB);
    if (jA >= dg){ pA = 0.f; sA = 0; }
    if (jB >= dg){ pB = 0.f; sB = 0; }
    uint4 vA = *(const uint4*)(hb + ((((unsigned)sA) << 7) | slb));
    uint4 vB = *(const uint4*)(hb + ((((unsigned)sB) << 7) | slb));
    FMA8(pA, vA)
    FMA8(pB, vB)
  }
  #pragma unroll
  for (int off = 8; off <= 32; off <<= 1){
    #pragma unroll
    for (int i = 0; i < 8; ++i) acc[i] += __shfl_xor(acc[i], off);
  }
  if (lane < 8){
    float4 b0 = ((const float4*)bias)[2 * sl];
    float4 b1 = ((const float4*)bias)[2 * sl + 1];
    float4 r0, r1;
    r0.x = acc[0] * inv + b0.x;
    r0.y = acc[1] * inv + b0.y;
    r0.z = acc[2] * inv + b0.z;
    r0.w = acc[3] * inv + b0.w;
    r1.x = acc[4] * inv + b1.x;
    r1.y = acc[5] * inv + b1.y;
    r1.z = acc[6] * inv + b1.z;
    r1.w = acc[7] * inv + b1.w;
    ((float4*)dout)[(size_t)w * 16 + 2 * sl]     = r0;
    ((float4*)dout)[(size_t)w * 16 + 2 * sl + 1] = r1;
  }
}

extern "C" void kernel_launch(void* const* d_in, const int* in_sizes, int n_in,
                              void* d_out, int out_size, void* d_ws, size_t ws_size,
                              hipStream_t stream) {
  const int*   x_ids    = (const int*)d_in[0];
  const int*   ei       = (const int*)d_in[1];
  const float* item_emb = (const float*)d_in[2];
  const float* W1       = (const float*)d_in[3];
  const float* att_src1 = (const float*)d_in[4];
  const float* att_dst1 = (const float*)d_in[5];
  const float* bias1    = (const float*)d_in[6];
  const float* W2       = (const float*)d_in[7];
  const float* att_src2 = (const float*)d_in[8];
  const float* att_dst2 = (const float*)d_in[9];
  const float* bias2    = (const float*)d_in[10];
  float* dout = (float*)d_out;

  int N  = in_sizes[0];
  int E  = in_sizes[1] / 2;
  int nbk  = (N + NBNODE - 1) / NBNODE;      // 782
  int nblk = (E + CHUNK - 1) / CHUNK;        // 391

  float* ws = (float*)d_ws;
  size_t o = 0;
  unsigned* h1bf = (unsigned*)(ws + o); o += (size_t)N * 64;   // layer1 lin rows (bf16x2)
  unsigned* h1p  = (unsigned*)(ws + o); o += (size_t)N * 64;   // layer1 output (bf16x2)
  unsigned* h2bf = (unsigned*)(ws + o); o += (size_t)N * 32;   // layer2 lin rows (bf16x2)
  float* a_src1 = ws + o; o += (size_t)N * 2;
  float* a_dst1 = ws + o; o += (size_t)N * 2;
  float* a_src2 = ws + o; o += N;
  float* a_dst2 = ws + o; o += N;
  int* deg  = (int*)(ws + o); o += N;
  int* csr  = (int*)(ws + o); o += (size_t)N * PAD;
  int* offs = (int*)(ws + o); o += (size_t)nblk * (nbk + 1);
  unsigned* w2p = (unsigned*)(ws + o); o += 4096;              // W2 B-fragments (16KB)
  o = (o + 3) & ~(size_t)3;                                    // 16B align
  unsigned* ebuf = (unsigned*)(ws + o); o += E;

  int gL1 = (N + 31) / 32;                       // lin1 blocks needed
  int M   = (gL1 + nblk - 1) / nblk + 1;         // interleave period (1 sort : M-1 lin1)
  int G   = nblk * M;

  int gW    = (N + 3) / 4;
  int ntile = (N + 15) / 16;
  int gL2m  = (ntile + 7) / 8;                   // 2 tiles per wave, 4 waves per block

  k_bl1<<<G, 256, 0, stream>>>(ei, E, N, nbk, nblk, M, offs, ebuf,
        x_ids, item_emb, W1, att_src1, att_dst1, h1bf, a_src1, a_dst1);
  k_build<<<nbk + 1, 256, 0, stream>>>(offs, ebuf, N, nbk, nblk, deg, csr, W2, w2p);
  k_gat1<<<gW, 256, 0, stream>>>(deg, csr, a_src1, a_dst1, h1bf, bias1, h1p, N);
  k_lin2m<<<gL2m, 256, 0, stream>>>(h1p, w2p, att_src2, att_dst2, h2bf, a_src2, a_dst2, N, ntile);
  k_gat2<<<gW, 256, 0, stream>>>(deg, csr, a_src2, a_dst2, h2bf, bias2, dout, N);
}

// Round 16
// 200.585 us; speedup vs baseline: 1.2501x; 1.0119x over previous
//
#include <hip/hip_runtime.h>
#include <hip/hip_bf16.h>

#define NEG_SLOPE 0.2f
#define PAD 64          // padded CSR row; slot 0 = self-loop, slots 1..63 = edges
#define NBNODE 128      // dst nodes per bucket
#define CHUNK 4096      // edges per sort block

typedef __attribute__((ext_vector_type(8))) short bf16x8;
typedef __attribute__((ext_vector_type(4))) float f32x4;

__device__ __forceinline__ float lrelu(float x){ return x >= 0.f ? x : NEG_SLOPE * x; }

__device__ __forceinline__ unsigned pack_bf16(float a, float b){
  unsigned ua = __float_as_uint(a), ub = __float_as_uint(b);
  ua = (ua + 0x7fffu + ((ua >> 16) & 1u)) >> 16;
  ub = (ub + 0x7fffu + ((ub >> 16) & 1u)) >> 16;
  return ua | (ub << 16);
}
__device__ __forceinline__ float bflo(unsigned u){ return __uint_as_float(u << 16); }
__device__ __forceinline__ float bfhi(unsigned u){ return __uint_as_float(u & 0xffff0000u); }

// ---------------- fused: chunk bucket-sort (no global atomics) + layer1 linear ----------------
__global__ __launch_bounds__(256) void k_bl1(const int* __restrict__ ei, int E, int N,
        int nbk, int nblk, int M,
        int* __restrict__ offs, unsigned* __restrict__ ebuf,
        const int* __restrict__ x_ids, const float* __restrict__ item_emb,
        const float* __restrict__ W1, const float* __restrict__ att_s, const float* __restrict__ att_d,
        unsigned* __restrict__ h1bf, float* __restrict__ a_src, float* __restrict__ a_dst){
  int b = blockIdx.x;
  int t = threadIdx.x;
  int lane = t & 63, wid = t >> 6;
  if (b % M == 0){
    int c = b / M;
    if (c >= nblk) return;
    __shared__ int lh[1024];     // histogram, then cursors
    __shared__ int st[1025];     // exclusive starts
    __shared__ int ws5[5];
    for (int i = t; i < nbk; i += 256) lh[i] = 0;
    __syncthreads();
    int ce = c * CHUNK;
    int cnt = E - ce; if (cnt > CHUNK) cnt = CHUNK;
    int es[16], ed[16];
    #pragma unroll
    for (int i = 0; i < 16; ++i){
      int e = t + i * 256;
      es[i] = 0; ed[i] = -1;
      if (e < cnt){
        es[i] = ei[ce + e];
        ed[i] = ei[E + ce + e];
        atomicAdd(&lh[ed[i] >> 7], 1);
      }
    }
    __syncthreads();
    int idx0 = t * 4;
    int v0 = 0, v1 = 0, v2 = 0, v3 = 0;
    if (idx0     < nbk) v0 = lh[idx0];
    if (idx0 + 1 < nbk) v1 = lh[idx0 + 1];
    if (idx0 + 2 < nbk) v2 = lh[idx0 + 2];
    if (idx0 + 3 < nbk) v3 = lh[idx0 + 3];
    int ts = v0 + v1 + v2 + v3;
    int x = ts;
    #pragma unroll
    for (int off = 1; off < 64; off <<= 1){
      int y = __shfl_up(x, off);
      if (lane >= off) x += y;
    }
    if (lane == 63) ws5[wid] = x;
    __syncthreads();
    if (t == 0){
      int a = 0;
      #pragma unroll
      for (int k = 0; k < 4; ++k){ int tmp = ws5[k]; ws5[k] = a; a += tmp; }
      ws5[4] = a;
      st[nbk] = a;
    }
    __syncthreads();
    int ex = x - ts + ws5[wid];
    if (idx0     < nbk) st[idx0]     = ex;
    if (idx0 + 1 < nbk) st[idx0 + 1] = ex + v0;
    if (idx0 + 2 < nbk) st[idx0 + 2] = ex + v0 + v1;
    if (idx0 + 3 < nbk) st[idx0 + 3] = ex + v0 + v1 + v2;
    __syncthreads();
    for (int i = t; i < nbk; i += 256) lh[i] = st[i];          // cursors
    for (int i = t; i <= nbk; i += 256) offs[(size_t)c * (nbk + 1) + i] = st[i];
    __syncthreads();
    #pragma unroll
    for (int i = 0; i < 16; ++i){
      int e = t + i * 256;
      if (e < cnt){
        int r = atomicAdd(&lh[ed[i] >> 7], 1);
        ebuf[(size_t)ce + r] = (unsigned)es[i] | ((unsigned)(ed[i] & 127) << 17);
      }
    }
    return;
  }
  // ---- lin1: W1 column-pair in registers, readlane broadcast, LDS-free ----
  int lid = (b / M) * (M - 1) + (b % M) - 1;
  int base = lid * 32 + wid * 8;
  if (base >= N) return;
  float2 w1c[32];
  const float2* W12 = (const float2*)W1;
  #pragma unroll
  for (int k = 0; k < 32; ++k) w1c[k] = W12[(k << 6) + lane];
  int c0 = 2 * lane;
  float as0 = att_s[c0], as1 = att_s[c0 + 1];
  float ad0 = att_d[c0], ad1 = att_d[c0 + 1];
  for (int it = 0; it < 8; ++it){
    int n = base + it;
    if (n >= N) break;
    float xv = 0.f;
    if (lane < 32){
      int id = x_ids[n];
      xv = (id == 0) ? 0.f : item_emb[(size_t)id * 32 + lane];
    }
    float acc0 = 0.f, acc1 = 0.f;
    #pragma unroll
    for (int k = 0; k < 32; ++k){
      float xk = __uint_as_float(__builtin_amdgcn_readlane(__float_as_uint(xv), k));
      acc0 += xk * w1c[k].x;
      acc1 += xk * w1c[k].y;
    }
    h1bf[(size_t)n * 64 + lane] = pack_bf16(acc0, acc1);
    float ps = acc0 * as0 + acc1 * as1;
    float pd = acc0 * ad0 + acc1 * ad1;
    #pragma unroll
    for (int off = 16; off; off >>= 1){
      ps += __shfl_xor(ps, off);
      pd += __shfl_xor(pd, off);
    }
    if ((lane & 31) == 0){
      int head = lane >> 5;
      a_src[n * 2 + head] = ps;
      a_dst[n * 2 + head] = pd;
    }
  }
}

// ---------------- per-bucket CSR build in LDS + W2 fragment pre-pack (last block) ----------------
__global__ __launch_bounds__(256) void k_build(const int* __restrict__ offs,
        const unsigned* __restrict__ ebuf, int N, int nbk, int nblk,
        int* __restrict__ deg, int* __restrict__ csr,
        const float* __restrict__ W2, unsigned* __restrict__ w2p){
  int b = blockIdx.x, t = threadIdx.x;
  if (b == nbk){
    for (int idx = t; idx < 1024; idx += 256){
      int kkct = idx >> 6, ln = idx & 63;
      int kk = kkct >> 2, ct = kkct & 3;
      int grp = ln >> 4, col16 = ln & 15;
      int kbase = kk * 32 + grp * 8;
      int col = ct * 16 + col16;
      uint4 v;
      v.x = pack_bf16(W2[(size_t)(kbase + 0) * 64 + col], W2[(size_t)(kbase + 1) * 64 + col]);
      v.y = pack_bf16(W2[(size_t)(kbase + 2) * 64 + col], W2[(size_t)(kbase + 3) * 64 + col]);
      v.z = pack_bf16(W2[(size_t)(kbase + 4) * 64 + col], W2[(size_t)(kbase + 5) * 64 + col]);
      v.w = pack_bf16(W2[(size_t)(kbase + 6) * 64 + col], W2[(size_t)(kbase + 7) * 64 + col]);
      ((uint4*)w2p)[idx] = v;
    }
    return;
  }
  __shared__ int lcsr[NBNODE * PAD];   // 32 KB
  __shared__ int ldeg[NBNODE];
  int base = b * NBNODE;
  int nn = N - base; if (nn > NBNODE) nn = NBNODE;
  for (int i = t; i < NBNODE; i += 256) ldeg[i] = 0;
  __syncthreads();
  for (int c = t; c < nblk; c += 256){
    size_t ob = (size_t)c * (nbk + 1) + b;
    int o0 = offs[ob];
    int o1 = offs[ob + 1];
    size_t ce = (size_t)c * CHUNK;
    for (int i = o0; i < o1; ++i){
      unsigned u = ebuf[ce + i];
      int ld = (int)(u >> 17);
      int s  = (int)(u & 0x1FFFFu);
      int slot = 1 + atomicAdd(&ldeg[ld], 1);
      if (slot < PAD) lcsr[(ld << 6) + slot] = s;
    }
  }
  __syncthreads();
  for (int i = t; i < nn; i += 256){
    int dv = ldeg[i];
    deg[base + i] = (dv > PAD - 1) ? (PAD - 1) : dv;
  }
  const uint4* l4 = (const uint4*)lcsr;
  uint4* g4 = (uint4*)(csr + ((size_t)base << 6));
  int n4 = nn * 16;
  for (int i = t; i < n4; i += 256) g4[i] = l4[i];
}

#define FMA8(P, V) \
  acc[0] += (P) * bflo((V).x); acc[1] += (P) * bfhi((V).x); \
  acc[2] += (P) * bflo((V).y); acc[3] += (P) * bfhi((V).y); \
  acc[4] += (P) * bflo((V).z); acc[5] += (P) * bfhi((V).z); \
  acc[6] += (P) * bflo((V).w); acc[7] += (P) * bfhi((V).w);

// ---------------- layer 1 fused attention + aggregation (bf16 rows in & out) ----------------
__global__ __launch_bounds__(256) void k_gat1(const int* __restrict__ deg, const int* __restrict__ csr,
        const float* __restrict__ a_src, const float* __restrict__ a_dst,
        const unsigned* __restrict__ hbf, const float* __restrict__ bias,
        unsigned* __restrict__ h1p, int N){
  int w = blockIdx.x * 4 + (threadIdx.x >> 6);
  int lane = threadIdx.x & 63;
  if (w >= N) return;
  int cnt = deg[w]; if (cnt > PAD - 1) cnt = PAD - 1;
  int dg = cnt + 1;
  int src_l = (lane == 0) ? w : ((lane < dg) ? csr[((size_t)w << 6) + lane] : 0);
  float2 ad = ((const float2*)a_dst)[w];
  float e0 = -__builtin_inff(), e1 = -__builtin_inff();
  if (lane < dg){
    float2 as = ((const float2*)a_src)[src_l];
    e0 = lrelu(as.x + ad.x);
    e1 = lrelu(as.y + ad.y);
  }
  float m0 = e0, m1 = e1;
  #pragma unroll
  for (int off = 32; off; off >>= 1){
    m0 = fmaxf(m0, __shfl_xor(m0, off));
    m1 = fmaxf(m1, __shfl_xor(m1, off));
  }
  float p0 = __expf(e0 - m0);
  float p1 = __expf(e1 - m1);
  float s0 = p0, s1 = p1;
  #pragma unroll
  for (int off = 32; off; off >>= 1){
    s0 += __shfl_xor(s0, off);
    s1 += __shfl_xor(s1, off);
  }
  float inv0 = 1.f / (s0 + 1e-16f);
  float inv1 = 1.f / (s1 + 1e-16f);
  unsigned ppk = pack_bf16(p0, p1);       // bf16 pair for one-shfl broadcast

  int g  = lane >> 4;            // edge group 0..3
  int sl = lane & 15;            // 16B slot in 256B row
  unsigned slb = (unsigned)sl * 16u;
  const char* hb = (const char*)hbf;
  float acc[8];
  #pragma unroll
  for (int i = 0; i < 8; ++i) acc[i] = 0.f;
  for (int i = 0; i < dg; i += 16){
    int jA = i + g, jB = i + 4 + g, jC = i + 8 + g, jD = i + 12 + g;
    int sA = __shfl(src_l, jA); unsigned kA = (unsigned)__shfl((int)ppk, jA);
    int sB = __shfl(src_l, jB); unsigned kB = (unsigned)__shfl((int)ppk, jB);
    int sC = __shfl(src_l, jC); unsigned kC = (unsigned)__shfl((int)ppk, jC);
    int sD = __shfl(src_l, jD); unsigned kD = (unsigned)__shfl((int)ppk, jD);
    float pA = (sl < 8) ? bflo(kA) : bfhi(kA); if (jA >= dg){ pA = 0.f; sA = 0; }
    float pB = (sl < 8) ? bflo(kB) : bfhi(kB); if (jB >= dg){ pB = 0.f; sB = 0; }
    float pC = (sl < 8) ? bflo(kC) : bfhi(kC); if (jC >= dg){ pC = 0.f; sC = 0; }
    float pD = (sl < 8) ? bflo(kD) : bfhi(kD); if (jD >= dg){ pD = 0.f; sD = 0; }
    uint4 vA = *(const uint4*)(hb + ((((unsigned)sA) << 8) | slb));
    uint4 vB = *(const uint4*)(hb + ((((unsigned)sB) << 8) | slb));
    uint4 vC = *(const uint4*)(hb + ((((unsigned)sC) << 8) | slb));
    uint4 vD = *(const uint4*)(hb + ((((unsigned)sD) << 8) | slb));
    FMA8(pA, vA)
    FMA8(pB, vB)
    FMA8(pC, vC)
    FMA8(pD, vD)
  }
  #pragma unroll
  for (int off = 16; off <= 32; off <<= 1){
    #pragma unroll
    for (int i = 0; i < 8; ++i) acc[i] += __shfl_xor(acc[i], off);
  }
  if (lane < 16){
    float inv = (sl < 8) ? inv0 : inv1;
    float4 b0 = ((const float4*)bias)[2 * sl];
    float4 b1 = ((const float4*)bias)[2 * sl + 1];
    float r0 = fmaxf(acc[0] * inv + b0.x, 0.f);
    float r1 = fmaxf(acc[1] * inv + b0.y, 0.f);
    float r2 = fmaxf(acc[2] * inv + b0.z, 0.f);
    float r3 = fmaxf(acc[3] * inv + b0.w, 0.f);
    float r4 = fmaxf(acc[4] * inv + b1.x, 0.f);
    float r5 = fmaxf(acc[5] * inv + b1.y, 0.f);
    float r6 = fmaxf(acc[6] * inv + b1.z, 0.f);
    float r7 = fmaxf(acc[7] * inv + b1.w, 0.f);
    uint4 pk;
    pk.x = pack_bf16(r0, r1);
    pk.y = pack_bf16(r2, r3);
    pk.z = pack_bf16(r4, r5);
    pk.w = pack_bf16(r6, r7);
    ((uint4*)h1p)[(size_t)w * 16 + sl] = pk;
  }
}

// ---------------- layer 2 linear via MFMA + attention dots ----------------
// wave per 16-node tile; B-fragments from pre-packed w2p (16 coalesced uint4).
__global__ __launch_bounds__(256) void k_lin2m(const unsigned* __restrict__ h1p,
        const unsigned* __restrict__ w2p, const float* __restrict__ att_s, const float* __restrict__ att_d,
        unsigned* __restrict__ h2bf, float* __restrict__ a_src, float* __restrict__ a_dst,
        int N, int ntile){
  int wid = threadIdx.x >> 6, lane = threadIdx.x & 63;
  int tile = blockIdx.x * 4 + wid;
  if (tile >= ntile) return;
  int col16 = lane & 15, grp = lane >> 4;
  bf16x8 bfr[4][4];
  const uint4* wp4 = (const uint4*)w2p;
  #pragma unroll
  for (int kk = 0; kk < 4; ++kk){
    #pragma unroll
    for (int ct = 0; ct < 4; ++ct){
      union { uint4 u; bf16x8 v; } cv;
      cv.u = wp4[(kk * 4 + ct) * 64 + lane];
      bfr[kk][ct] = cv.v;
    }
  }
  const uint4* hp = (const uint4*)h1p;
  int row = tile * 16 + col16;
  int arow = (row < N) ? row : N - 1;      // clamp OOB rows (stores guarded)
  f32x4 cc[4];
  #pragma unroll
  for (int ct = 0; ct < 4; ++ct) cc[ct] = (f32x4){0.f, 0.f, 0.f, 0.f};
  #pragma unroll
  for (int kk = 0; kk < 4; ++kk){
    union { uint4 u; bf16x8 v; } ac;
    ac.u = hp[(size_t)arow * 16 + kk * 4 + grp];
    cc[0] = __builtin_amdgcn_mfma_f32_16x16x32_bf16(ac.v, bfr[kk][0], cc[0], 0, 0, 0);
    cc[1] = __builtin_amdgcn_mfma_f32_16x16x32_bf16(ac.v, bfr[kk][1], cc[1], 0, 0, 0);
    cc[2] = __builtin_amdgcn_mfma_f32_16x16x32_bf16(ac.v, bfr[kk][2], cc[2], 0, 0, 0);
    cc[3] = __builtin_amdgcn_mfma_f32_16x16x32_bf16(ac.v, bfr[kk][3], cc[3], 0, 0, 0);
  }
  float dsv[4] = {0.f, 0.f, 0.f, 0.f}, ddv[4] = {0.f, 0.f, 0.f, 0.f};
  #pragma unroll
  for (int ct = 0; ct < 4; ++ct){
    float asc = att_s[ct * 16 + col16];
    float adc = att_d[ct * 16 + col16];
    #pragma unroll
    for (int r = 0; r < 4; ++r){
      dsv[r] += cc[ct][r] * asc;
      ddv[r] += cc[ct][r] * adc;
    }
  }
  #pragma unroll
  for (int off = 1; off <= 8; off <<= 1){
    #pragma unroll
    for (int r = 0; r < 4; ++r){
      dsv[r] += __shfl_xor(dsv[r], off);
      ddv[r] += __shfl_xor(ddv[r], off);
    }
  }
  if (col16 == 0){
    #pragma unroll
    for (int r = 0; r < 4; ++r){
      int n = tile * 16 + grp * 4 + r;
      if (n < N){ a_src[n] = dsv[r]; a_dst[n] = ddv[r]; }
    }
  }
  #pragma unroll
  for (int ct = 0; ct < 4; ++ct){
    #pragma unroll
    for (int r = 0; r < 4; ++r){
      float own = cc[ct][r];
      float pr  = __shfl_xor(own, 1);
      if (!(lane & 1)){
        int n = tile * 16 + grp * 4 + r;
        if (n < N)
          h2bf[(size_t)n * 32 + ct * 8 + (col16 >> 1)] = pack_bf16(own, pr);
      }
    }
  }
}

// ---------------- layer 2 fused attention + aggregation (bf16 rows) ----------------
__global__ __launch_bounds__(256) void k_gat2(const int* __restrict__ deg, const int* __restrict__ csr,
        const float* __restrict__ a_src, const float* __restrict__ a_dst,
        const unsigned* __restrict__ hbf, const float* __restrict__ bias,
        float* __restrict__ dout, int N){
  int w = blockIdx.x * 4 + (threadIdx.x >> 6);
  int lane = threadIdx.x & 63;
  if (w >= N) return;
  int cnt = deg[w]; if (cnt > PAD - 1) cnt = PAD - 1;
  int dg = cnt + 1;
  int src_l = (lane == 0) ? w : ((lane < dg) ? csr[((size_t)w << 6) + lane] : 0);
  float ad = a_dst[w];
  float e = -__builtin_inff();
  if (lane < dg) e = lrelu(a_src[src_l] + ad);
  float m = e;
  #pragma unroll
  for (int off = 32; off; off >>= 1) m = fmaxf(m, __shfl_xor(m, off));
  float p = __expf(e - m);
  float ssum = p;
  #pragma unroll
  for (int off = 32; off; off >>= 1) ssum += __shfl_xor(ssum, off);
  float inv = 1.f / (ssum + 1e-16f);

  int g  = lane >> 3;            // edge group 0..7
  int sl = lane & 7;             // 16B slot in 128B row
  unsigned slb = (unsigned)sl * 16u;
  const char* hb = (const char*)hbf;
  float acc[8];
  #pragma unroll
  for (int i = 0; i < 8; ++i) acc[i] = 0.f;
  for (int i = 0; i < dg; i += 16){
    int jA = i + g, jB = i + 8 + g;
    int sA = __shfl(src_l, jA); float pA = __shfl(p, jA);
    int sB = __shfl(src_l, jB); float pB = __shfl(p, jB);
    if (jA >= dg){ pA = 0.f; sA = 0; }
    if (jB >= dg){ pB = 0.f; sB = 0; }
    uint4 vA = *(const uint4*)(hb + ((((unsigned)sA) << 7) | slb));
    uint4 vB = *(const uint4*)(hb + ((((unsigned)sB) << 7) | slb));
    FMA8(pA, vA)
    FMA8(pB, vB)
  }
  #pragma unroll
  for (int off = 8; off <= 32; off <<= 1){
    #pragma unroll
    for (int i = 0; i < 8; ++i) acc[i] += __shfl_xor(acc[i], off);
  }
  if (lane < 8){
    float4 b0 = ((const float4*)bias)[2 * sl];
    float4 b1 = ((const float4*)bias)[2 * sl + 1];
    float4 r0, r1;
    r0.x = acc[0] * inv + b0.x;
    r0.y = acc[1] * inv + b0.y;
    r0.z = acc[2] * inv + b0.z;
    r0.w = acc[3] * inv + b0.w;
    r1.x = acc[4] * inv + b1.x;
    r1.y = acc[5] * inv + b1.y;
    r1.z = acc[6] * inv + b1.z;
    r1.w = acc[7] * inv + b1.w;
    ((float4*)dout)[(size_t)w * 16 + 2 * sl]     = r0;
    ((float4*)dout)[(size_t)w * 16 + 2 * sl + 1] = r1;
  }
}

extern "C" void kernel_launch(void* const* d_in, const int* in_sizes, int n_in,
                              void* d_out, int out_size, void* d_ws, size_t ws_size,
                              hipStream_t stream) {
  const int*   x_ids    = (const int*)d_in[0];
  const int*   ei       = (const int*)d_in[1];
  const float* item_emb = (const float*)d_in[2];
  const float* W1       = (const float*)d_in[3];
  const float* att_src1 = (const float*)d_in[4];
  const float* att_dst1 = (const float*)d_in[5];
  const float* bias1    = (const float*)d_in[6];
  const float* W2       = (const float*)d_in[7];
  const float* att_src2 = (const float*)d_in[8];
  const float* att_dst2 = (const float*)d_in[9];
  const float* bias2    = (const float*)d_in[10];
  float* dout = (float*)d_out;

  int N  = in_sizes[0];
  int E  = in_sizes[1] / 2;
  int nbk  = (N + NBNODE - 1) / NBNODE;      // 782
  int nblk = (E + CHUNK - 1) / CHUNK;        // 391

  float* ws = (float*)d_ws;
  size_t o = 0;
  unsigned* h1bf = (unsigned*)(ws + o); o += (size_t)N * 64;   // layer1 lin rows (bf16x2)
  unsigned* h1p  = (unsigned*)(ws + o); o += (size_t)N * 64;   // layer1 output (bf16x2)
  unsigned* h2bf = (unsigned*)(ws + o); o += (size_t)N * 32;   // layer2 lin rows (bf16x2)
  float* a_src1 = ws + o; o += (size_t)N * 2;
  float* a_dst1 = ws + o; o += (size_t)N * 2;
  float* a_src2 = ws + o; o += N;
  float* a_dst2 = ws + o; o += N;
  int* deg  = (int*)(ws + o); o += N;
  int* csr  = (int*)(ws + o); o += (size_t)N * PAD;
  int* offs = (int*)(ws + o); o += (size_t)nblk * (nbk + 1);
  unsigned* w2p = (unsigned*)(ws + o); o += 4096;              // W2 B-fragments (16KB)
  o = (o + 3) & ~(size_t)3;                                    // 16B align
  unsigned* ebuf = (unsigned*)(ws + o); o += E;

  int gL1 = (N + 31) / 32;                       // lin1 blocks needed
  int M   = (gL1 + nblk - 1) / nblk + 1;         // interleave period (1 sort : M-1 lin1)
  int G   = nblk * M;

  int gW    = (N + 3) / 4;
  int ntile = (N + 15) / 16;
  int gL2m  = (ntile + 3) / 4;                   // 1 tile per wave, 4 waves per block

  k_bl1<<<G, 256, 0, stream>>>(ei, E, N, nbk, nblk, M, offs, ebuf,
        x_ids, item_emb, W1, att_src1, att_dst1, h1bf, a_src1, a_dst1);
  k_build<<<nbk + 1, 256, 0, stream>>>(offs, ebuf, N, nbk, nblk, deg, csr, W2, w2p);
  k_gat1<<<gW, 256, 0, stream>>>(deg, csr, a_src1, a_dst1, h1bf, bias1, h1p, N);
  k_lin2m<<<gL2m, 256, 0, stream>>>(h1p, w2p, att_src2, att_dst2, h2bf, a_src2, a_dst2, N, ntile);
  k_gat2<<<gW, 256, 0, stream>>>(deg, csr, a_src2, a_dst2, h2bf, bias2, dout, N);
}

// Round 17
// 193.696 us; speedup vs baseline: 1.2946x; 1.0356x over previous
//
#include <hip/hip_runtime.h>
#include <hip/hip_bf16.h>
#include <hip/hip_fp16.h>

#define NEG_SLOPE 0.2f
#define PAD 64          // padded CSR row; slot 0 = self-loop, slots 1..63 = edges
#define NBNODE 128      // dst nodes per bucket
#define CHUNK 4096      // edges per sort block

typedef _Float16 __attribute__((ext_vector_type(8))) f16x8;
typedef __attribute__((ext_vector_type(4))) float f32x4;

__device__ __forceinline__ float lrelu(float x){ return x >= 0.f ? x : NEG_SLOPE * x; }

__device__ __forceinline__ __half2 u2h(unsigned u){ __half2 h; __builtin_memcpy(&h, &u, 4); return h; }
__device__ __forceinline__ unsigned h2u(__half2 h){ unsigned u; __builtin_memcpy(&u, &h, 4); return u; }
__device__ __forceinline__ unsigned packh(float a, float b){ return h2u(__floats2half2_rn(a, b)); }

// ---------------- fused: chunk bucket-sort (no global atomics) + layer1 linear ----------------
__global__ __launch_bounds__(256) void k_bl1(const int* __restrict__ ei, int E, int N,
        int nbk, int nblk, int M,
        int* __restrict__ offs, unsigned* __restrict__ ebuf,
        const int* __restrict__ x_ids, const float* __restrict__ item_emb,
        const float* __restrict__ W1, const float* __restrict__ att_s, const float* __restrict__ att_d,
        unsigned* __restrict__ h1bf, float* __restrict__ a_src, float* __restrict__ a_dst){
  int b = blockIdx.x;
  int t = threadIdx.x;
  int lane = t & 63, wid = t >> 6;
  if (b % M == 0){
    int c = b / M;
    if (c >= nblk) return;
    __shared__ int lh[1024];     // histogram, then cursors
    __shared__ int st[1025];     // exclusive starts
    __shared__ int ws5[5];
    for (int i = t; i < nbk; i += 256) lh[i] = 0;
    __syncthreads();
    int ce = c * CHUNK;
    int cnt = E - ce; if (cnt > CHUNK) cnt = CHUNK;
    int es[16], ed[16];
    #pragma unroll
    for (int i = 0; i < 16; ++i){
      int e = t + i * 256;
      es[i] = 0; ed[i] = -1;
      if (e < cnt){
        es[i] = ei[ce + e];
        ed[i] = ei[E + ce + e];
        atomicAdd(&lh[ed[i] >> 7], 1);
      }
    }
    __syncthreads();
    int idx0 = t * 4;
    int v0 = 0, v1 = 0, v2 = 0, v3 = 0;
    if (idx0     < nbk) v0 = lh[idx0];
    if (idx0 + 1 < nbk) v1 = lh[idx0 + 1];
    if (idx0 + 2 < nbk) v2 = lh[idx0 + 2];
    if (idx0 + 3 < nbk) v3 = lh[idx0 + 3];
    int ts = v0 + v1 + v2 + v3;
    int x = ts;
    #pragma unroll
    for (int off = 1; off < 64; off <<= 1){
      int y = __shfl_up(x, off);
      if (lane >= off) x += y;
    }
    if (lane == 63) ws5[wid] = x;
    __syncthreads();
    if (t == 0){
      int a = 0;
      #pragma unroll
      for (int k = 0; k < 4; ++k){ int tmp = ws5[k]; ws5[k] = a; a += tmp; }
      ws5[4] = a;
      st[nbk] = a;
    }
    __syncthreads();
    int ex = x - ts + ws5[wid];
    if (idx0     < nbk) st[idx0]     = ex;
    if (idx0 + 1 < nbk) st[idx0 + 1] = ex + v0;
    if (idx0 + 2 < nbk) st[idx0 + 2] = ex + v0 + v1;
    if (idx0 + 3 < nbk) st[idx0 + 3] = ex + v0 + v1 + v2;
    __syncthreads();
    for (int i = t; i < nbk; i += 256) lh[i] = st[i];          // cursors
    for (int i = t; i <= nbk; i += 256) offs[(size_t)c * (nbk + 1) + i] = st[i];
    __syncthreads();
    #pragma unroll
    for (int i = 0; i < 16; ++i){
      int e = t + i * 256;
      if (e < cnt){
        int r = atomicAdd(&lh[ed[i] >> 7], 1);
        ebuf[(size_t)ce + r] = (unsigned)es[i] | ((unsigned)(ed[i] & 127) << 17);
      }
    }
    return;
  }
  // ---- lin1: W1 column-pair in registers, readlane broadcast, LDS-free ----
  int lid = (b / M) * (M - 1) + (b % M) - 1;
  int base = lid * 32 + wid * 8;
  if (base >= N) return;
  float2 w1c[32];
  const float2* W12 = (const float2*)W1;
  #pragma unroll
  for (int k = 0; k < 32; ++k) w1c[k] = W12[(k << 6) + lane];
  int c0 = 2 * lane;
  float as0 = att_s[c0], as1 = att_s[c0 + 1];
  float ad0 = att_d[c0], ad1 = att_d[c0 + 1];
  for (int it = 0; it < 8; ++it){
    int n = base + it;
    if (n >= N) break;
    float xv = 0.f;
    if (lane < 32){
      int id = x_ids[n];
      xv = (id == 0) ? 0.f : item_emb[(size_t)id * 32 + lane];
    }
    float acc0 = 0.f, acc1 = 0.f;
    #pragma unroll
    for (int k = 0; k < 32; ++k){
      float xk = __uint_as_float(__builtin_amdgcn_readlane(__float_as_uint(xv), k));
      acc0 += xk * w1c[k].x;
      acc1 += xk * w1c[k].y;
    }
    h1bf[(size_t)n * 64 + lane] = packh(acc0, acc1);
    float ps = acc0 * as0 + acc1 * as1;
    float pd = acc0 * ad0 + acc1 * ad1;
    #pragma unroll
    for (int off = 16; off; off >>= 1){
      ps += __shfl_xor(ps, off);
      pd += __shfl_xor(pd, off);
    }
    if ((lane & 31) == 0){
      int head = lane >> 5;
      a_src[n * 2 + head] = ps;
      a_dst[n * 2 + head] = pd;
    }
  }
}

// ---------------- per-bucket CSR build in LDS + W2 fragment pre-pack (last block) ----------------
__global__ __launch_bounds__(256) void k_build(const int* __restrict__ offs,
        const unsigned* __restrict__ ebuf, int N, int nbk, int nblk,
        int* __restrict__ deg, int* __restrict__ csr,
        const float* __restrict__ W2, unsigned* __restrict__ w2p){
  int b = blockIdx.x, t = threadIdx.x;
  if (b == nbk){
    for (int idx = t; idx < 1024; idx += 256){
      int kkct = idx >> 6, ln = idx & 63;
      int kk = kkct >> 2, ct = kkct & 3;
      int grp = ln >> 4, col16 = ln & 15;
      int kbase = kk * 32 + grp * 8;
      int col = ct * 16 + col16;
      uint4 v;
      v.x = packh(W2[(size_t)(kbase + 0) * 64 + col], W2[(size_t)(kbase + 1) * 64 + col]);
      v.y = packh(W2[(size_t)(kbase + 2) * 64 + col], W2[(size_t)(kbase + 3) * 64 + col]);
      v.z = packh(W2[(size_t)(kbase + 4) * 64 + col], W2[(size_t)(kbase + 5) * 64 + col]);
      v.w = packh(W2[(size_t)(kbase + 6) * 64 + col], W2[(size_t)(kbase + 7) * 64 + col]);
      ((uint4*)w2p)[idx] = v;
    }
    return;
  }
  __shared__ int lcsr[NBNODE * PAD];   // 32 KB
  __shared__ int ldeg[NBNODE];
  int base = b * NBNODE;
  int nn = N - base; if (nn > NBNODE) nn = NBNODE;
  for (int i = t; i < NBNODE; i += 256) ldeg[i] = 0;
  __syncthreads();
  for (int c = t; c < nblk; c += 256){
    size_t ob = (size_t)c * (nbk + 1) + b;
    int o0 = offs[ob];
    int o1 = offs[ob + 1];
    size_t ce = (size_t)c * CHUNK;
    for (int i = o0; i < o1; ++i){
      unsigned u = ebuf[ce + i];
      int ld = (int)(u >> 17);
      int s  = (int)(u & 0x1FFFFu);
      int slot = 1 + atomicAdd(&ldeg[ld], 1);
      if (slot < PAD) lcsr[(ld << 6) + slot] = s;
    }
  }
  __syncthreads();
  for (int i = t; i < nn; i += 256){
    int dv = ldeg[i];
    deg[base + i] = (dv > PAD - 1) ? (PAD - 1) : dv;
  }
  const uint4* l4 = (const uint4*)lcsr;
  uint4* g4 = (uint4*)(csr + ((size_t)base << 6));
  int n4 = nn * 16;
  for (int i = t; i < n4; i += 256) g4[i] = l4[i];
}

#define HFMA4(PM, V) \
  acc[0] = h2u(__hfma2(u2h(PM), u2h((V).x), u2h(acc[0]))); \
  acc[1] = h2u(__hfma2(u2h(PM), u2h((V).y), u2h(acc[1]))); \
  acc[2] = h2u(__hfma2(u2h(PM), u2h((V).z), u2h(acc[2]))); \
  acc[3] = h2u(__hfma2(u2h(PM), u2h((V).w), u2h(acc[3])));

// ---------------- layer 1 fused attention + aggregation (fp16 rows, pk_fma) ----------------
__global__ __launch_bounds__(256) void k_gat1(const int* __restrict__ deg, const int* __restrict__ csr,
        const float* __restrict__ a_src, const float* __restrict__ a_dst,
        const unsigned* __restrict__ hbf, const float* __restrict__ bias,
        unsigned* __restrict__ h1p, int N){
  int w = blockIdx.x * 4 + (threadIdx.x >> 6);
  int lane = threadIdx.x & 63;
  if (w >= N) return;
  int cnt = deg[w]; if (cnt > PAD - 1) cnt = PAD - 1;
  int dg = cnt + 1;
  int src_l = (lane == 0) ? w : ((lane < dg) ? csr[((size_t)w << 6) + lane] : 0);
  float2 ad = ((const float2*)a_dst)[w];
  float e0 = -__builtin_inff(), e1 = -__builtin_inff();
  if (lane < dg){
    float2 as = ((const float2*)a_src)[src_l];
    e0 = lrelu(as.x + ad.x);
    e1 = lrelu(as.y + ad.y);
  }
  float m0 = e0, m1 = e1;
  #pragma unroll
  for (int off = 32; off; off >>= 1){
    m0 = fmaxf(m0, __shfl_xor(m0, off));
    m1 = fmaxf(m1, __shfl_xor(m1, off));
  }
  float p0 = __expf(e0 - m0);   // lane>=dg: exp(-inf)=0
  float p1 = __expf(e1 - m1);
  float s0 = p0, s1 = p1;
  #pragma unroll
  for (int off = 32; off; off >>= 1){
    s0 += __shfl_xor(s0, off);
    s1 += __shfl_xor(s1, off);
  }
  float inv0 = 1.f / (s0 + 1e-16f);
  float inv1 = 1.f / (s1 + 1e-16f);
  unsigned ppk = packh(p0, p1);   // fp16 pair; zero for padding lanes

  int g  = lane >> 4;            // edge group 0..3
  int sl = lane & 15;            // 16B slot in 256B row
  unsigned sh = (sl < 8) ? 0u : 16u;   // head select shift
  unsigned slb = (unsigned)sl * 16u;
  const char* hb = (const char*)hbf;
  unsigned acc[4] = {0u, 0u, 0u, 0u};  // 4x half2 = 8 channels
  for (int i = 0; i < dg; i += 16){
    int jA = i + g, jB = i + 4 + g, jC = i + 8 + g, jD = i + 12 + g;
    int sA = __shfl(src_l, jA); unsigned kA = (unsigned)__shfl((int)ppk, jA);
    int sB = __shfl(src_l, jB); unsigned kB = (unsigned)__shfl((int)ppk, jB);
    int sC = __shfl(src_l, jC); unsigned kC = (unsigned)__shfl((int)ppk, jC);
    int sD = __shfl(src_l, jD); unsigned kD = (unsigned)__shfl((int)ppk, jD);
    unsigned tA = (kA >> sh) & 0xffffu; unsigned pA = tA | (tA << 16);
    unsigned tB = (kB >> sh) & 0xffffu; unsigned pB = tB | (tB << 16);
    unsigned tC = (kC >> sh) & 0xffffu; unsigned pC = tC | (tC << 16);
    unsigned tD = (kD >> sh) & 0xffffu; unsigned pD = tD | (tD << 16);
    uint4 vA = *(const uint4*)(hb + ((((unsigned)sA) << 8) | slb));
    uint4 vB = *(const uint4*)(hb + ((((unsigned)sB) << 8) | slb));
    uint4 vC = *(const uint4*)(hb + ((((unsigned)sC) << 8) | slb));
    uint4 vD = *(const uint4*)(hb + ((((unsigned)sD) << 8) | slb));
    HFMA4(pA, vA)
    HFMA4(pB, vB)
    HFMA4(pC, vC)
    HFMA4(pD, vD)
  }
  #pragma unroll
  for (int off = 16; off <= 32; off <<= 1){
    #pragma unroll
    for (int i = 0; i < 4; ++i)
      acc[i] = h2u(__hadd2(u2h(acc[i]), u2h((unsigned)__shfl_xor((int)acc[i], off))));
  }
  if (lane < 16){
    float inv = (sl < 8) ? inv0 : inv1;
    float2 c0 = __half22float2(u2h(acc[0]));
    float2 c1 = __half22float2(u2h(acc[1]));
    float2 c2 = __half22float2(u2h(acc[2]));
    float2 c3 = __half22float2(u2h(acc[3]));
    float4 b0 = ((const float4*)bias)[2 * sl];
    float4 b1 = ((const float4*)bias)[2 * sl + 1];
    float r0 = fmaxf(c0.x * inv + b0.x, 0.f);
    float r1 = fmaxf(c0.y * inv + b0.y, 0.f);
    float r2 = fmaxf(c1.x * inv + b0.z, 0.f);
    float r3 = fmaxf(c1.y * inv + b0.w, 0.f);
    float r4 = fmaxf(c2.x * inv + b1.x, 0.f);
    float r5 = fmaxf(c2.y * inv + b1.y, 0.f);
    float r6 = fmaxf(c3.x * inv + b1.z, 0.f);
    float r7 = fmaxf(c3.y * inv + b1.w, 0.f);
    uint4 pk;
    pk.x = packh(r0, r1);
    pk.y = packh(r2, r3);
    pk.z = packh(r4, r5);
    pk.w = packh(r6, r7);
    ((uint4*)h1p)[(size_t)w * 16 + sl] = pk;
  }
}

// ---------------- layer 2 linear via MFMA (f16) + attention dots ----------------
__global__ __launch_bounds__(256) void k_lin2m(const unsigned* __restrict__ h1p,
        const unsigned* __restrict__ w2p, const float* __restrict__ att_s, const float* __restrict__ att_d,
        unsigned* __restrict__ h2bf, float* __restrict__ a_src, float* __restrict__ a_dst,
        int N, int ntile){
  int wid = threadIdx.x >> 6, lane = threadIdx.x & 63;
  int tile = blockIdx.x * 4 + wid;
  if (tile >= ntile) return;
  int col16 = lane & 15, grp = lane >> 4;
  f16x8 bfr[4][4];
  const uint4* wp4 = (const uint4*)w2p;
  #pragma unroll
  for (int kk = 0; kk < 4; ++kk){
    #pragma unroll
    for (int ct = 0; ct < 4; ++ct){
      union { uint4 u; f16x8 v; } cv;
      cv.u = wp4[(kk * 4 + ct) * 64 + lane];
      bfr[kk][ct] = cv.v;
    }
  }
  const uint4* hp = (const uint4*)h1p;
  int row = tile * 16 + col16;
  int arow = (row < N) ? row : N - 1;      // clamp OOB rows (stores guarded)
  f32x4 cc[4];
  #pragma unroll
  for (int ct = 0; ct < 4; ++ct) cc[ct] = (f32x4){0.f, 0.f, 0.f, 0.f};
  #pragma unroll
  for (int kk = 0; kk < 4; ++kk){
    union { uint4 u; f16x8 v; } ac;
    ac.u = hp[(size_t)arow * 16 + kk * 4 + grp];
    cc[0] = __builtin_amdgcn_mfma_f32_16x16x32_f16(ac.v, bfr[kk][0], cc[0], 0, 0, 0);
    cc[1] = __builtin_amdgcn_mfma_f32_16x16x32_f16(ac.v, bfr[kk][1], cc[1], 0, 0, 0);
    cc[2] = __builtin_amdgcn_mfma_f32_16x16x32_f16(ac.v, bfr[kk][2], cc[2], 0, 0, 0);
    cc[3] = __builtin_amdgcn_mfma_f32_16x16x32_f16(ac.v, bfr[kk][3], cc[3], 0, 0, 0);
  }
  float dsv[4] = {0.f, 0.f, 0.f, 0.f}, ddv[4] = {0.f, 0.f, 0.f, 0.f};
  #pragma unroll
  for (int ct = 0; ct < 4; ++ct){
    float asc = att_s[ct * 16 + col16];
    float adc = att_d[ct * 16 + col16];
    #pragma unroll
    for (int r = 0; r < 4; ++r){
      dsv[r] += cc[ct][r] * asc;
      ddv[r] += cc[ct][r] * adc;
    }
  }
  #pragma unroll
  for (int off = 1; off <= 8; off <<= 1){
    #pragma unroll
    for (int r = 0; r < 4; ++r){
      dsv[r] += __shfl_xor(dsv[r], off);
      ddv[r] += __shfl_xor(ddv[r], off);
    }
  }
  if (col16 == 0){
    #pragma unroll
    for (int r = 0; r < 4; ++r){
      int n = tile * 16 + grp * 4 + r;
      if (n < N){ a_src[n] = dsv[r]; a_dst[n] = ddv[r]; }
    }
  }
  #pragma unroll
  for (int ct = 0; ct < 4; ++ct){
    #pragma unroll
    for (int r = 0; r < 4; ++r){
      float own = cc[ct][r];
      float pr  = __shfl_xor(own, 1);
      if (!(lane & 1)){
        int n = tile * 16 + grp * 4 + r;
        if (n < N)
          h2bf[(size_t)n * 32 + ct * 8 + (col16 >> 1)] = packh(own, pr);
      }
    }
  }
}

// ---------------- layer 2 fused attention + aggregation (fp16 rows, pk_fma) ----------------
__global__ __launch_bounds__(256) void k_gat2(const int* __restrict__ deg, const int* __restrict__ csr,
        const float* __restrict__ a_src, const float* __restrict__ a_dst,
        const unsigned* __restrict__ hbf, const float* __restrict__ bias,
        float* __restrict__ dout, int N){
  int w = blockIdx.x * 4 + (threadIdx.x >> 6);
  int lane = threadIdx.x & 63;
  if (w >= N) return;
  int cnt = deg[w]; if (cnt > PAD - 1) cnt = PAD - 1;
  int dg = cnt + 1;
  int src_l = (lane == 0) ? w : ((lane < dg) ? csr[((size_t)w << 6) + lane] : 0);
  float ad = a_dst[w];
  float e = -__builtin_inff();
  if (lane < dg) e = lrelu(a_src[src_l] + ad);
  float m = e;
  #pragma unroll
  for (int off = 32; off; off >>= 1) m = fmaxf(m, __shfl_xor(m, off));
  float p = __expf(e - m);   // 0 for padding lanes
  float ssum = p;
  #pragma unroll
  for (int off = 32; off; off >>= 1) ssum += __shfl_xor(ssum, off);
  float inv = 1.f / (ssum + 1e-16f);
  unsigned ppk = packh(p, p);   // both halves = p: no head select needed

  int g  = lane >> 3;            // edge group 0..7
  int sl = lane & 7;             // 16B slot in 128B row
  unsigned slb = (unsigned)sl * 16u;
  const char* hb = (const char*)hbf;
  unsigned acc[4] = {0u, 0u, 0u, 0u};
  for (int i = 0; i < dg; i += 16){
    int jA = i + g, jB = i + 8 + g;
    int sA = __shfl(src_l, jA); unsigned pA = (unsigned)__shfl((int)ppk, jA);
    int sB = __shfl(src_l, jB); unsigned pB = (unsigned)__shfl((int)ppk, jB);
    uint4 vA = *(const uint4*)(hb + ((((unsigned)sA) << 7) | slb));
    uint4 vB = *(const uint4*)(hb + ((((unsigned)sB) << 7) | slb));
    HFMA4(pA, vA)
    HFMA4(pB, vB)
  }
  #pragma unroll
  for (int off = 8; off <= 32; off <<= 1){
    #pragma unroll
    for (int i = 0; i < 4; ++i)
      acc[i] = h2u(__hadd2(u2h(acc[i]), u2h((unsigned)__shfl_xor((int)acc[i], off))));
  }
  if (lane < 8){
    float2 c0 = __half22float2(u2h(acc[0]));
    float2 c1 = __half22float2(u2h(acc[1]));
    float2 c2 = __half22float2(u2h(acc[2]));
    float2 c3 = __half22float2(u2h(acc[3]));
    float4 b0 = ((const float4*)bias)[2 * sl];
    float4 b1 = ((const float4*)bias)[2 * sl + 1];
    float4 r0, r1;
    r0.x = c0.x * inv + b0.x;
    r0.y = c0.y * inv + b0.y;
    r0.z = c1.x * inv + b0.z;
    r0.w = c1.y * inv + b0.w;
    r1.x = c2.x * inv + b1.x;
    r1.y = c2.y * inv + b1.y;
    r1.z = c3.x * inv + b1.z;
    r1.w = c3.y * inv + b1.w;
    ((float4*)dout)[(size_t)w * 16 + 2 * sl]     = r0;
    ((float4*)dout)[(size_t)w * 16 + 2 * sl + 1] = r1;
  }
}

extern "C" void kernel_launch(void* const* d_in, const int* in_sizes, int n_in,
                              void* d_out, int out_size, void* d_ws, size_t ws_size,
                              hipStream_t stream) {
  const int*   x_ids    = (const int*)d_in[0];
  const int*   ei       = (const int*)d_in[1];
  const float* item_emb = (const float*)d_in[2];
  const float* W1       = (const float*)d_in[3];
  const float* att_src1 = (const float*)d_in[4];
  const float* att_dst1 = (const float*)d_in[5];
  const float* bias1    = (const float*)d_in[6];
  const float* W2       = (const float*)d_in[7];
  const float* att_src2 = (const float*)d_in[8];
  const float* att_dst2 = (const float*)d_in[9];
  const float* bias2    = (const float*)d_in[10];
  float* dout = (float*)d_out;

  int N  = in_sizes[0];
  int E  = in_sizes[1] / 2;
  int nbk  = (N + NBNODE - 1) / NBNODE;      // 782
  int nblk = (E + CHUNK - 1) / CHUNK;        // 391

  float* ws = (float*)d_ws;
  size_t o = 0;
  unsigned* h1bf = (unsigned*)(ws + o); o += (size_t)N * 64;   // layer1 lin rows (fp16x2)
  unsigned* h1p  = (unsigned*)(ws + o); o += (size_t)N * 64;   // layer1 output (fp16x2)
  unsigned* h2bf = (unsigned*)(ws + o); o += (size_t)N * 32;   // layer2 lin rows (fp16x2)
  float* a_src1 = ws + o; o += (size_t)N * 2;
  float* a_dst1 = ws + o; o += (size_t)N * 2;
  float* a_src2 = ws + o; o += N;
  float* a_dst2 = ws + o; o += N;
  int* deg  = (int*)(ws + o); o += N;
  int* csr  = (int*)(ws + o); o += (size_t)N * PAD;
  int* offs = (int*)(ws + o); o += (size_t)nblk * (nbk + 1);
  unsigned* w2p = (unsigned*)(ws + o); o += 4096;              // W2 B-fragments (16KB)
  o = (o + 3) & ~(size_t)3;                                    // 16B align
  unsigned* ebuf = (unsigned*)(ws + o); o += E;

  int gL1 = (N + 31) / 32;                       // lin1 blocks needed
  int M   = (gL1 + nblk - 1) / nblk + 1;         // interleave period (1 sort : M-1 lin1)
  int G   = nblk * M;

  int gW    = (N + 3) / 4;
  int ntile = (N + 15) / 16;
  int gL2m  = (ntile + 3) / 4;                   // 1 tile per wave, 4 waves per block

  k_bl1<<<G, 256, 0, stream>>>(ei, E, N, nbk, nblk, M, offs, ebuf,
        x_ids, item_emb, W1, att_src1, att_dst1, h1bf, a_src1, a_dst1);
  k_build<<<nbk + 1, 256, 0, stream>>>(offs, ebuf, N, nbk, nblk, deg, csr, W2, w2p);
  k_gat1<<<gW, 256, 0, stream>>>(deg, csr, a_src1, a_dst1, h1bf, bias1, h1p, N);
  k_lin2m<<<gL2m, 256, 0, stream>>>(h1p, w2p, att_src2, att_dst2, h2bf, a_src2, a_dst2, N, ntile);
  k_gat2<<<gW, 256, 0, stream>>>(deg, csr, a_src2, a_dst2, h2bf, bias2, dout, N);
}